// Round 8
// baseline (1359.277 us; speedup 1.0000x reference)
//
#include <hip/hip_runtime.h>

typedef unsigned short u16;
typedef unsigned int   u32;
typedef short   short8  __attribute__((ext_vector_type(8)));
typedef float   floatx4 __attribute__((ext_vector_type(4)));
typedef int     intx4   __attribute__((ext_vector_type(4)));

#define NTOK 8192
#define SEQ  512
#define NLAYER 6

// ---- workspace layout (bytes) ----
#define OFF_WT   ((size_t)0)          // transposed weights (bf16), 19,005,440 u16
#define OFF_HB   ((size_t)38010880)   // h bf16   [8192][512] (residual stream)
#define OFF_QKV  ((size_t)46399488)   // qkv bf16 [8192][1536] (25.2 MB)
#define OFF_CTX  ((size_t)71565312)   // ctx bf16 [8192][512]
#define OFF_GOUT ((size_t)79953920)   // gout0 fp32 [8192][512]
#define OFF_FF   ((size_t)96731136)   // ff bf16  [8192][2048]  (33.5 MB)
#define OFF_HD1  ((size_t)130285568)  // head1 bf16 [8192][256] (4.2 MB)
// aliases:
//   gout1 (split-K partial, f32 [8192][512]) -> qkv region (dead during Wo/FFN2)
//   vT bf16 [128 bh][64][512] (8.4 MB) -> ff region (dead during attn)
//   relB_all bf16 [6][272][64] (209 KB) -> hd1 region (hd1 written only at end)
#define OFF_VT   OFF_FF
#define OFF_RELB OFF_HD1

#define LSTRIDE 3145728   // wT elems per layer: [QT;KT;VT](1536x512), WoT, w1T(2048x512), w2T(512x2048)
#define P1T_OFF 18874368  // p1T [256][512]

__device__ __forceinline__ float b2f(u16 v) { return __uint_as_float(((u32)v) << 16); }
__device__ __forceinline__ float lo16(u32 v) { return __uint_as_float(v << 16); }
__device__ __forceinline__ float hi16(u32 v) { return __uint_as_float(v & 0xffff0000u); }
__device__ __forceinline__ u16 f2b(float f) {
  u32 x = __float_as_uint(f);
  return (u16)((x + 0x7fffu + ((x >> 16) & 1u)) >> 16);
}
__device__ __forceinline__ u32 pack2(float a, float b) {
  return (u32)f2b(a) | ((u32)f2b(b) << 16);
}
__device__ __forceinline__ u32 cvtpk(float a, float b) {
  u32 r;
  asm("v_cvt_pk_bf16_f32 %0, %1, %2" : "=v"(r) : "v"(a), "v"(b));
  return r;
}

typedef __attribute__((address_space(1))) void* gas_t;
typedef __attribute__((address_space(3))) void* las_t;

// ---------------------------------------------------------------------------
// Transpose all f32 weight matrices into wT, in MFMA-FRAGMENT-PACKED layout:
// element (n,k) of logical Bt[N][K] lives at
//   (((n>>7)*(K>>5) + (k>>5))*8 + ((n>>4)&7))*512
//   + (((k>>3)&3)*16 + (n&15))*8 + (k&7)
// so fragment (nb,kc,j) is 512 contiguous u16 and lane l's short8 is at l*8:
// gemm_bt loads B operands straight from global as coalesced 1 KB reads
// (no LDS staging for B at all). Per-matrix size unchanged (N*K elems) ->
// all wT offsets including fused-QKV sub-blocks are preserved.
// ---------------------------------------------------------------------------
__global__ __launch_bounds__(256) void transpose_all(
    const float* __restrict__ Wq, const float* __restrict__ Wk,
    const float* __restrict__ Wv, const float* __restrict__ Wo,
    const float* __restrict__ w1, const float* __restrict__ w2,
    const float* __restrict__ p1, u16* __restrict__ wT)
{
  __shared__ u16 tile[64][65];
  const int tb = blockIdx.x;
  const float* src; u16* dst; int R, C, tidx;
  if (tb < 4608) {
    const int l = tb / 768, r = tb % 768;
    const size_t lofs = (size_t)l * LSTRIDE;
    if (r < 256) {
      const int m = r >> 6; tidx = r & 63; R = 512; C = 512;
      const float* bases[4] = {Wq, Wk, Wv, Wo};
      src = bases[m] + (size_t)l * 262144;
      dst = wT + lofs + (size_t)m * 262144;
    } else if (r < 512) {
      tidx = r - 256; R = 512; C = 2048;
      src = w1 + (size_t)l * 1048576; dst = wT + lofs + 1048576;
    } else {
      tidx = r - 512; R = 2048; C = 512;
      src = w2 + (size_t)l * 1048576; dst = wT + lofs + 2097152;
    }
  } else {
    tidx = tb - 4608; R = 512; C = 256;
    src = p1; dst = wT + P1T_OFF;
  }
  // src is W[R=K][C=N]; logical dst Bt[N][K] but stored fragment-packed.
  const int tcn = C >> 6;
  const int tr = tidx / tcn, tc = tidx % tcn;
  const int th = threadIdx.x;
  {
    const int lr = th >> 2, cg = (th & 3) * 16;
    const float* sp = src + (size_t)(tr*64 + lr) * C + tc*64 + cg;
    float4 f0 = *(const float4*)(sp);
    float4 f1 = *(const float4*)(sp + 4);
    float4 f2 = *(const float4*)(sp + 8);
    float4 f3 = *(const float4*)(sp + 12);
    u16* tp = &tile[lr][cg];
    tp[0]=f2b(f0.x); tp[1]=f2b(f0.y); tp[2]=f2b(f0.z); tp[3]=f2b(f0.w);
    tp[4]=f2b(f1.x); tp[5]=f2b(f1.y); tp[6]=f2b(f1.z); tp[7]=f2b(f1.w);
    tp[8]=f2b(f2.x); tp[9]=f2b(f2.y); tp[10]=f2b(f2.z); tp[11]=f2b(f2.w);
    tp[12]=f2b(f3.x); tp[13]=f2b(f3.y); tp[14]=f2b(f3.z); tp[15]=f2b(f3.w);
  }
  __syncthreads();
  {
    const int oc = th >> 2, rg = (th & 3) * 16;
    u32 wds[8];
    #pragma unroll
    for (int i = 0; i < 8; ++i)
      wds[i] = (u32)tile[rg + 2*i][oc] | ((u32)tile[rg + 2*i + 1][oc] << 16);
    const int n  = tc*64 + oc;            // N-dim index
    const int k0 = tr*64 + rg;            // K-dim index, 16-aligned
    const int nb = n >> 7, j = (n >> 4) & 7, lr = n & 15;
    const int kc = k0 >> 5, lq = (k0 >> 3) & 3;   // lq in {0,2}
    const int KC = R >> 5;
    u16* base = dst + (((((size_t)nb*KC + kc) << 3) + j) << 9);
    uint4 o0; o0.x=wds[0]; o0.y=wds[1]; o0.z=wds[2]; o0.w=wds[3];
    uint4 o1; o1.x=wds[4]; o1.y=wds[5]; o1.z=wds[6]; o1.w=wds[7];
    *(uint4*)(base + (lq*16 + lr)*8)       = o0;  // k0..k0+7
    *(uint4*)(base + ((lq+1)*16 + lr)*8)   = o1;  // k0+8..k0+15
  }
}

// ---------------------------------------------------------------------------
// h = x @ in_w + in_b + sinusoidal_pe   (K=50) -> bf16
// Each thread owns 4 consecutive d: 50 float4 loads, 2 __sincosf.
// ---------------------------------------------------------------------------
__global__ __launch_bounds__(128) void input_proj(
    const float* __restrict__ x, const float* __restrict__ w, const float* __restrict__ ib,
    u16* __restrict__ hb)
{
  const int row = blockIdx.x, t = threadIdx.x;
  const int s = row & (SEQ - 1);
  __shared__ float xs[50];
  if (t < 50) xs[t] = x[row*50 + t];
  __syncthreads();
  const int d0 = t * 4;                    // even; covers 512 with 128 threads
  float4 acc = *(const float4*)(ib + d0);
  #pragma unroll
  for (int i = 0; i < 50; ++i) {
    const float4 wv = *(const float4*)(w + i*512 + d0);
    const float xv = xs[i];
    acc.x = fmaf(xv, wv.x, acc.x);
    acc.y = fmaf(xv, wv.y, acc.y);
    acc.z = fmaf(xv, wv.z, acc.z);
    acc.w = fmaf(xv, wv.w, acc.w);
  }
  const float cexp = -0.017988946f;        // -ln(10000)/512
  const float dv0 = __expf((float)d0 * cexp);
  const float dv1 = __expf((float)(d0 + 2) * cexp);
  float s0, c0, s1, c1;
  __sincosf((float)s * dv0, &s0, &c0);
  __sincosf((float)s * dv1, &s1, &c1);
  acc.x += s0; acc.y += c0; acc.z += s1; acc.w += c1;
  u32* hp = (u32*)(hb + (size_t)row*512 + d0);
  hp[0] = pack2(acc.x, acc.y);
  hp[1] = pack2(acc.z, acc.w);
}

// ---------------------------------------------------------------------------
// C[M][N] = A[M][K] @ Bt[N][K]^T over k in [z*kLen, (z+1)*kLen)
// R6: B consumed directly from global in fragment-packed layout; only A is
// LDS-staged (double-buffered 2x16 KB). (Unchanged in R8.)
// ---------------------------------------------------------------------------
__global__ __launch_bounds__(256, 4) void gemm_bt(
    const u16* __restrict__ A, const u16* __restrict__ Bt,
    const float* __restrict__ bias,
    float* __restrict__ outF0, float* __restrict__ outF1, u16* __restrict__ outB,
    u16* __restrict__ vTout,
    const int M, const int N, const int K, const int kLen, const int flags)
{
  __shared__ __align__(16) u16 As[2][8192];   // [buf][hh*4096 + row*32 + k32]
  const int id = blockIdx.x;
  const int xcd = id & 7, rest = id >> 3;
  const int bm = (rest & 7) * 8 + xcd;
  const int bn = rest >> 3;
  const int z = blockIdx.y;
  const int kOff = z * kLen;
  const int m0 = bm << 7, n0 = bn << 7;
  const int tid = threadIdx.x;
  const int wave = tid >> 6, lane = tid & 63;
  const int wr = (wave >> 1) << 6, wc = (wave & 1) << 6;
  const int lrow = lane & 15, lquad = lane >> 4;

  floatx4 acc[4][4];
  #pragma unroll
  for (int i = 0; i < 4; ++i)
    #pragma unroll
    for (int j = 0; j < 4; ++j) { floatx4 zz = {0.f,0.f,0.f,0.f}; acc[i][j] = zz; }

  const u16* a0p = A + (size_t)m0 * K + kOff;
  const int c0 = tid, c1 = 256 + tid;
  const int ar0 = c0 >> 2, as0 = (c0 & 3) * 8;
  const int ar1 = c1 >> 2, as1 = (c1 & 3) * 8;
  const int KC = K >> 5;
  // base of this wave's B-fragment stream: (bn, kc=kOff/32, jglob=(wave&1)*4)
  const u16* bW = Bt + ((((size_t)bn*KC + (kOff >> 5)) * 8 + (wave & 1) * 4) << 9) + lane*8;

#define STAGE_A(buf, k0) do {                                                                  \
    __builtin_amdgcn_global_load_lds((gas_t)(a0p + (size_t)ar0*K + (k0) + as0),                \
                                     (las_t)(&As[buf][c0*8]), 16, 0, 0);                       \
    __builtin_amdgcn_global_load_lds((gas_t)(a0p + (size_t)ar1*K + (k0) + as1),                \
                                     (las_t)(&As[buf][c1*8]), 16, 0, 0);                       \
    __builtin_amdgcn_global_load_lds((gas_t)(a0p + (size_t)ar0*K + (k0) + 32 + as0),           \
                                     (las_t)(&As[buf][4096 + c0*8]), 16, 0, 0);                \
    __builtin_amdgcn_global_load_lds((gas_t)(a0p + (size_t)ar1*K + (k0) + 32 + as1),           \
                                     (las_t)(&As[buf][4096 + c1*8]), 16, 0, 0);                \
  } while (0)

  const int nst = kLen >> 6;
  STAGE_A(0, 0);
  __syncthreads();

  int cur = 0;
  for (int t = 0; t < nst; ++t) {
    // B fragments for this chunk, straight from global (packed layout).
    const u16* bc = bW + (size_t)(2*t) * 4096;
    short8 b0[4], b1[4];
    #pragma unroll
    for (int j = 0; j < 4; ++j) b0[j] = *(const short8*)(bc + j*512);
    if (t + 1 < nst) STAGE_A(cur ^ 1, (t + 1) * 64);
    #pragma unroll
    for (int j = 0; j < 4; ++j) b1[j] = *(const short8*)(bc + 4096 + j*512);
    // hh = 0
    {
      short8 af[4];
      #pragma unroll
      for (int i = 0; i < 4; ++i) af[i] = *(const short8*)&As[cur][(wr + i*16 + lrow)*32 + lquad*8];
      #pragma unroll
      for (int i = 0; i < 4; ++i)
        #pragma unroll
        for (int j = 0; j < 4; ++j)
          acc[i][j] = __builtin_amdgcn_mfma_f32_16x16x32_bf16(b0[j], af[i], acc[i][j], 0, 0, 0);
    }
    // hh = 1
    {
      short8 af[4];
      #pragma unroll
      for (int i = 0; i < 4; ++i) af[i] = *(const short8*)&As[cur][4096 + (wr + i*16 + lrow)*32 + lquad*8];
      #pragma unroll
      for (int i = 0; i < 4; ++i)
        #pragma unroll
        for (int j = 0; j < 4; ++j)
          acc[i][j] = __builtin_amdgcn_mfma_f32_16x16x32_bf16(b1[j], af[i], acc[i][j], 0, 0, 0);
    }
    if (t + 1 < nst) { __syncthreads(); cur ^= 1; }
  }
#undef STAGE_A

  // Swapped layout: lane owns row = m0+wr+i*16+lrow (fixed),
  //                 cols = n0+wc+j*16+lquad*4 + v (v=0..3 consecutive)
  if ((flags & 4) && n0 >= 1024) {
    // V block of QKV: write into vT[(b*8+h)*64+d][s] (bf16), scalar stores
    #pragma unroll
    for (int i = 0; i < 4; ++i) {
      const int row = m0 + wr + i*16 + lrow;
      const int bb = row >> 9, s = row & 511;
      #pragma unroll
      for (int j = 0; j < 4; ++j) {
        const int cm0 = (n0 - 1024) + wc + j*16 + lquad*4;
        #pragma unroll
        for (int v = 0; v < 4; ++v) {
          const int cm = cm0 + v;
          const int hh = cm >> 6, d = cm & 63;
          vTout[((size_t)(bb*8 + hh)*64 + d)*512 + s] = f2b(acc[i][j][v]);
        }
      }
    }
    return;
  }

  float* outF = (z == 0) ? outF0 : outF1;
  const bool hasb = ((flags & 1) != 0) && (z == 0);
  const bool dorelu = (flags & 2) != 0;
  #pragma unroll
  for (int i = 0; i < 4; ++i) {
    const int row = m0 + wr + i*16 + lrow;
    #pragma unroll
    for (int j = 0; j < 4; ++j) {
      const int colbase = n0 + wc + j*16 + lquad*4;
      float4 bv4 = make_float4(0.f, 0.f, 0.f, 0.f);
      if (hasb) bv4 = *(const float4*)(bias + colbase);
      float v0 = acc[i][j][0] + bv4.x;
      float v1 = acc[i][j][1] + bv4.y;
      float v2 = acc[i][j][2] + bv4.z;
      float v3 = acc[i][j][3] + bv4.w;
      if (dorelu) {
        v0 = fmaxf(v0, 0.f); v1 = fmaxf(v1, 0.f);
        v2 = fmaxf(v2, 0.f); v3 = fmaxf(v3, 0.f);
      }
      const size_t off = (size_t)row * N + colbase;
      if (outB) {
        uint2 o; o.x = pack2(v0, v1); o.y = pack2(v2, v3);
        *(uint2*)(outB + off) = o;
      } else {
        *(float4*)(outF + off) = make_float4(v0, v1, v2, v3);
      }
    }
  }
}

// ---------------------------------------------------------------------------
// All layers' rel_emb f32 [6][257][64] -> bf16 relB_all [6][272][64]
// ---------------------------------------------------------------------------
__global__ __launch_bounds__(256) void cvt_rel_all(
    const float* __restrict__ rel, u16* __restrict__ relB)
{
  const int i = blockIdx.x*256 + threadIdx.x;
  if (i < 6*257*64) {
    const int l = i / 16448, rem = i % 16448;
    relB[l*17408 + rem] = f2b(rel[i]);
  }
}

// ---------------------------------------------------------------------------
// MFMA flash attention, S^T / register-P version.
// R8: LDS cut to EXACTLY 40,960 B -> 4 blocks/CU resident -> all 1024 blocks
// run in ONE round (was 3 blocks/CU -> 768 + 256-block straggler tail; the
// tail was the measured 22.9% occupancy). Changes:
//  - Vs LDS DROPPED: PV A-fragments read straight from global vT[d][s]
//    (row-contiguous direction, L2-resident 64KB/block; issued after barrier
//    B, consumed after softmax -> latency hidden). Unlike R1's K-from-global
//    (3 KB row stride), V reads are 8B at 32B spacing in 128B segments.
//  - Ks stride 72 -> 64 with XOR swizzle byte^=(row&7)<<4 on BOTH write and
//    read (same bank spread as stride-72; write side improves to 2-way).
//  - Pr stride 274 -> 256: table holds dd in [-128,+127]; the +128 boundary
//    is stashed via the (not yet used) Ks buffer into a register prHi
//    (same-wave 16-row slab, in-order DS pipe -> no barrier needed).
// Keeps: band-specialized bias paths (R7), register-P PV (R3), T14 K
// prefetch, T5 setprio.
// LDS: Ks 8192 + Pr 32768 = 40960 B = 160KB/4.
// ---------------------------------------------------------------------------
__global__ __launch_bounds__(256, 4) void attn_mfma(
    const u16* __restrict__ qkv, const u16* __restrict__ vT,
    const u16* __restrict__ relB, u16* __restrict__ ctx)
{
  const int id = blockIdx.x;
  const int xcd = id & 7, g = (id >> 3) & 15, qt = id >> 7;
  const int bh = xcd*16 + g;
  const int b = bh >> 3, h = bh & 7;
  const int t = threadIdx.x, w = t >> 6, lane = t & 63;
  const int lr = lane & 15, quad = lane >> 4;

  __shared__ __align__(16) u16 Ks[64*64];   // XOR-swizzled: byte ^= (row&7)<<4
  __shared__ __align__(16) u16 Pr[64*256];  // bias*log2e, dd in [-128,127]

  const size_t token0 = (size_t)b*512 + qt*64;
  const int srow = t >> 2, scol = (t & 3) * 16;
  const u16* kbase = qkv + (size_t)b*512*1536 + 512 + h*64;
  const u16* vbase = vT + (size_t)bh*64*512;

  // Q fragment (needed immediately for Pr build)
  short8 af0, af1;
  {
    const u16* qp = qkv + (token0 + w*16 + lr)*1536 + h*64 + quad*8;
    af0 = *(const short8*)(qp);
    af1 = *(const short8*)(qp + 32);
  }

  // prefetch kt=0 K into regs; latency hides under Pr build below
  uint4 kr0, kr1;
  {
    const u16* kp = kbase + (size_t)srow*1536 + scol;
    kr0 = *(const uint4*)kp; kr1 = *(const uint4*)(kp + 8);
  }

  // Pr[q][j] = (Q[q] . relB[j]) * log2(e), j in [0,256) -> dd = j-128.
  // Rows w*16+quad*4+r are wave-private; read side uses rows w*16+lr ->
  // same 16-row slab, same wave -> in-order DS pipe, no barrier (R3-proven).
  #pragma unroll 4
  for (int nt = 0; nt < 16; ++nt) {
    const u16* rp = relB + (nt*16 + lr)*64 + quad*8;
    short8 rb0 = *(const short8*)(rp);
    short8 rb1 = *(const short8*)(rp + 32);
    floatx4 c = {0.f,0.f,0.f,0.f};
    c = __builtin_amdgcn_mfma_f32_16x16x32_bf16(af0, rb0, c, 0, 0, 0);
    c = __builtin_amdgcn_mfma_f32_16x16x32_bf16(af1, rb1, c, 0, 0, 0);
    #pragma unroll
    for (int r = 0; r < 4; ++r)
      Pr[(w*16 + quad*4 + r)*256 + nt*16 + lr] = f2b(c[r] * 1.44269504f);
  }
  // boundary column j=256 (dd=+128): compute, stash via Ks, read back to reg.
  {
    const u16* rp = relB + (256 + lr)*64 + quad*8;   // lr>0 rows are pad; results discarded
    short8 rb0 = *(const short8*)(rp);
    short8 rb1 = *(const short8*)(rp + 32);
    floatx4 c = {0.f,0.f,0.f,0.f};
    c = __builtin_amdgcn_mfma_f32_16x16x32_bf16(af0, rb0, c, 0, 0, 0);
    c = __builtin_amdgcn_mfma_f32_16x16x32_bf16(af1, rb1, c, 0, 0, 0);
    if (lr == 0) {
      #pragma unroll
      for (int r = 0; r < 4; ++r)
        Ks[w*16 + quad*4 + r] = f2b(c[r] * 1.44269504f);
    }
  }
  const float prHi = b2f(Ks[w*16 + lr]);        // dd = +128 (same-wave slab)
  const float prLo = b2f(Pr[(w*16 + lr)*256]);  // dd = -128

  floatx4 oacc[4];
  float lacc = 0.f;
  #pragma unroll
  for (int n = 0; n < 4; ++n) { floatx4 zz = {0.f,0.f,0.f,0.f}; oacc[n] = zz; }

  const int qglob = qt*64 + w*16 + lr;          // this lane's q (global)
  const int prbase = (w*16 + lr)*256 + 128;     // Pr row base + offset

  for (int kt = 0; kt < 8; ++kt) {
    __syncthreads();  // A: prev iter's Ks readers done before overwrite
    {
      const int swz = (srow & 7) << 4;
      char* kb = (char*)Ks;
      *(uint4*)(kb + ((srow*128 + scol*2) ^ swz))      = kr0;
      *(uint4*)(kb + ((srow*128 + scol*2 + 16) ^ swz)) = kr1;
    }
    __syncthreads();  // B: staging visible

    // V fragments for THIS kt straight from global (vT row-contiguous);
    // issued now, consumed after softmax -> latency hidden under QK+exp.
    uint2 va[4][4];
    #pragma unroll
    for (int nd = 0; nd < 4; ++nd) {
      const u16* vp = vbase + (size_t)(nd*16 + lr)*512 + kt*64 + quad*4;
      va[nd][0] = *(const uint2*)(vp);
      va[nd][1] = *(const uint2*)(vp + 16);
      va[nd][2] = *(const uint2*)(vp + 32);
      va[nd][3] = *(const uint2*)(vp + 48);
    }
    // T14: issue NEXT tile's K loads now; consumed at next iter's write.
    if (kt < 7) {
      const u16* kp = kbase + (size_t)((kt+1)*64 + srow)*1536 + scol;
      kr0 = *(const uint4*)kp; kr1 = *(const uint4*)(kp + 8);
    }

    // S^T = K . Q^T  (lane: col=lr -> q fixed, row=quad*4+r -> k-local)
    floatx4 s4[4];
    __builtin_amdgcn_s_setprio(1);
    #pragma unroll
    for (int nt = 0; nt < 4; ++nt) {
      const int row = nt*16 + lr;
      const char* kbp = (const char*)Ks + row*128;
      const int swz = (lr & 7) << 4;
      short8 kb0 = *(const short8*)(kbp + ((quad*16) ^ swz));
      short8 kb1 = *(const short8*)(kbp + ((64 + quad*16) ^ swz));
      floatx4 c = {0.f,0.f,0.f,0.f};
      c = __builtin_amdgcn_mfma_f32_16x16x32_bf16(kb0, af0, c, 0, 0, 0);
      c = __builtin_amdgcn_mfma_f32_16x16x32_bf16(kb1, af1, c, 0, 0, 0);
      s4[nt] = c;
    }
    __builtin_amdgcn_s_setprio(0);

    // P = exp2(S*0.125*log2e + bias), packed to bf16 pairs.
    // Wave-uniform tile classification vs the clamp band:
    const int tmin = kt*64 - (qt*64 + w*16 + 15);   // min dd over wave tile
    const int tmax = tmin + 78;                     // max dd
    u32 wq[4][2];
    const int kq = kt*64 + quad*4 - qglob;
    if (tmin >= 128 || tmax <= -128) {
      // fully clamped: bias constant per lane
      const float pc = (tmin >= 128) ? prHi : prLo;
      #pragma unroll
      for (int nt = 0; nt < 4; ++nt) {
        float p[4];
        #pragma unroll
        for (int r = 0; r < 4; ++r)
          p[r] = exp2f(fmaf(s4[nt][r], 0.18033688f, pc));
        lacc += (p[0] + p[1]) + (p[2] + p[3]);
        wq[nt][0] = cvtpk(p[0], p[1]);
        wq[nt][1] = cvtpk(p[2], p[3]);
      }
    } else if (tmin >= -128 && tmax <= 127) {
      // interior: direct table read, no clamp
      #pragma unroll
      for (int nt = 0; nt < 4; ++nt) {
        const int dbase = kq + nt*16;
        float p[4];
        #pragma unroll
        for (int r = 0; r < 4; ++r)
          p[r] = exp2f(fmaf(s4[nt][r], 0.18033688f, b2f(Pr[prbase + dbase + r])));
        lacc += (p[0] + p[1]) + (p[2] + p[3]);
        wq[nt][0] = cvtpk(p[0], p[1]);
        wq[nt][1] = cvtpk(p[2], p[3]);
      }
    } else {
      // partial: clamped gather; dd>=128 -> prHi register
      #pragma unroll
      for (int nt = 0; nt < 4; ++nt) {
        const int dbase = kq + nt*16;
        float p[4];
        #pragma unroll
        for (int r = 0; r < 4; ++r) {
          const int dd = dbase + r;
          int di = dd < -128 ? -128 : (dd > 127 ? 127 : dd);
          const float bias = (dd >= 128) ? prHi : b2f(Pr[prbase + di]);
          p[r] = exp2f(fmaf(s4[nt][r], 0.18033688f, bias));
        }
        lacc += (p[0] + p[1]) + (p[2] + p[3]);
        wq[nt][0] = cvtpk(p[0], p[1]);
        wq[nt][1] = cvtpk(p[2], p[3]);
      }
    }

    // PV B-fragments assembled in registers (sigma absorbed into va reads)
    intx4 pw0; pw0.x = (int)wq[0][0]; pw0.y = (int)wq[0][1];
               pw0.z = (int)wq[1][0]; pw0.w = (int)wq[1][1];
    intx4 pw1; pw1.x = (int)wq[2][0]; pw1.y = (int)wq[2][1];
               pw1.z = (int)wq[3][0]; pw1.w = (int)wq[3][1];
    const short8 pf0 = __builtin_bit_cast(short8, pw0);
    const short8 pf1 = __builtin_bit_cast(short8, pw1);

    // O += V x P : A-frag vb[row=d][kk] = V^T[d][sigma(kk)];
    // sigma(kk = quad*8+j) = (j>>2)*16 + quad*4 + (j&3)  (+32 for pf1 half)
    __builtin_amdgcn_s_setprio(1);
    #pragma unroll
    for (int nd = 0; nd < 4; ++nd) {
      intx4 v0; v0.x = (int)va[nd][0].x; v0.y = (int)va[nd][0].y;
                v0.z = (int)va[nd][1].x; v0.w = (int)va[nd][1].y;
      intx4 v1; v1.x = (int)va[nd][2].x; v1.y = (int)va[nd][2].y;
                v1.z = (int)va[nd][3].x; v1.w = (int)va[nd][3].y;
      const short8 vb0 = __builtin_bit_cast(short8, v0);
      const short8 vb1 = __builtin_bit_cast(short8, v1);
      oacc[nd] = __builtin_amdgcn_mfma_f32_16x16x32_bf16(vb0, pf0, oacc[nd], 0, 0, 0);
      oacc[nd] = __builtin_amdgcn_mfma_f32_16x16x32_bf16(vb1, pf1, oacc[nd], 0, 0, 0);
    }
    __builtin_amdgcn_s_setprio(0);
  }

  // cross-quad denominator reduce (q = lr is shared by the 4 quads)
  lacc += __shfl_xor(lacc, 16);
  lacc += __shfl_xor(lacc, 32);

  // epilogue: q = lr (fixed per lane); lane writes d = nd*16 + quad*4 + v
  {
    const float inv = 1.f / lacc;
    u16* cp = ctx + (token0 + w*16 + lr)*512 + h*64;
    #pragma unroll
    for (int nd = 0; nd < 4; ++nd) {
      const int d = nd*16 + quad*4;
      uint2 o;
      o.x = pack2(oacc[nd][0]*inv, oacc[nd][1]*inv);
      o.y = pack2(oacc[nd][2]*inv, oacc[nd][3]*inv);
      *(uint2*)(cp + d) = o;
    }
  }
}

// ---------------------------------------------------------------------------
// LayerNorm over D=512: h = LN(b2f(resB) (+ add0) (+ add1)) * g + b -> hb
// ---------------------------------------------------------------------------
__global__ __launch_bounds__(128) void ln_kernel(
    const u16* __restrict__ resB, const float* __restrict__ add0,
    const float* __restrict__ add1,
    const float* __restrict__ g, const float* __restrict__ be,
    u16* __restrict__ hb)
{
  const int row = blockIdx.x, t = threadIdx.x;
  const size_t base = (size_t)row * 512;
  const u32 r0 = *(const u32*)(resB + base + t*4);
  const u32 r1 = *(const u32*)(resB + base + t*4 + 2);
  float x0 = lo16(r0), x1 = hi16(r0), x2 = lo16(r1), x3 = hi16(r1);
  if (add0) {
    const float4 a = *(const float4*)(add0 + base + t*4);
    x0 += a.x; x1 += a.y; x2 += a.z; x3 += a.w;
  }
  if (add1) {
    const float4 a = *(const float4*)(add1 + base + t*4);
    x0 += a.x; x1 += a.y; x2 += a.z; x3 += a.w;
  }
  float s = x0 + x1 + x2 + x3;
  #pragma unroll
  for (int off = 32; off > 0; off >>= 1) s += __shfl_down(s, off);
  __shared__ float red[2];
  const int wv = t >> 6, ln = t & 63;
  if (ln == 0) red[wv] = s;
  __syncthreads();
  const float mean = (red[0] + red[1]) * (1.f/512.f);
  const float dx0 = x0-mean, dx1 = x1-mean, dx2 = x2-mean, dx3 = x3-mean;
  float vs = dx0*dx0 + dx1*dx1 + dx2*dx2 + dx3*dx3;
  __syncthreads();
  #pragma unroll
  for (int off = 32; off > 0; off >>= 1) vs += __shfl_down(vs, off);
  if (ln == 0) red[wv] = vs;
  __syncthreads();
  const float var = (red[0] + red[1]) * (1.f/512.f);
  const float inv = 1.f / sqrtf(var + 1e-5f);
  const float4 gv = *(const float4*)(g + t*4);
  const float4 bv = *(const float4*)(be + t*4);
  const float y0 = dx0*inv*gv.x + bv.x;
  const float y1 = dx1*inv*gv.y + bv.y;
  const float y2 = dx2*inv*gv.z + bv.z;
  const float y3 = dx3*inv*gv.w + bv.w;
  u32* hp = (u32*)(hb + base + t*4);
  hp[0] = pack2(y0, y1); hp[1] = pack2(y2, y3);
}

// ---------------------------------------------------------------------------
// out[row] = hd1[row][:] . p2_w + p2_b   (256-dot, one wave per row), f32 out
// ---------------------------------------------------------------------------
__global__ __launch_bounds__(256) void head2_kernel(
    const u16* __restrict__ hd1, const float* __restrict__ p2w,
    const float* __restrict__ p2b, float* __restrict__ out)
{
  const int wv = threadIdx.x >> 6, ln = threadIdx.x & 63;
  const int row = blockIdx.x * 4 + wv;
  const u16* hp = hd1 + (size_t)row * 256 + ln*4;
  const u32 h0 = *(const u32*)hp, h1 = *(const u32*)(hp + 2);
  const float4 w = *(const float4*)(p2w + ln*4);
  float acc = lo16(h0)*w.x + hi16(h0)*w.y + lo16(h1)*w.z + hi16(h1)*w.w;
  #pragma unroll
  for (int off = 1; off < 64; off <<= 1) acc += __shfl_xor(acc, off);
  if (ln == 0) out[row] = acc + p2b[0];
}

// ---------------------------------------------------------------------------
extern "C" void kernel_launch(void* const* d_in, const int* in_sizes, int n_in,
                              void* d_out, int out_size, void* d_ws, size_t ws_size,
                              hipStream_t stream) {
  (void)in_sizes; (void)n_in; (void)out_size; (void)ws_size;
  const float* X    = (const float*)d_in[0];
  const float* INW  = (const float*)d_in[1];
  const float* INB  = (const float*)d_in[2];
  const float* WQ   = (const float*)d_in[3];
  const float* WK   = (const float*)d_in[4];
  const float* WV   = (const float*)d_in[5];
  const float* WO   = (const float*)d_in[6];
  const float* BO   = (const float*)d_in[7];
  const float* REL  = (const float*)d_in[8];
  const float* W1   = (const float*)d_in[9];
  const float* B1   = (const float*)d_in[10];
  const float* W2   = (const float*)d_in[11];
  const float* B2   = (const float*)d_in[12];
  const float* LN1G = (const float*)d_in[13];
  const float* LN1B = (const float*)d_in[14];
  const float* LN2G = (const float*)d_in[15];
  const float* LN2B = (const float*)d_in[16];
  const float* ONG  = (const float*)d_in[17];
  const float* ONB  = (const float*)d_in[18];
  const float* P1W  = (const float*)d_in[19];
  const float* P1B  = (const float*)d_in[20];
  const float* P2W  = (const float*)d_in[21];
  const float* P2B  = (const float*)d_in[22];
  float* out = (float*)d_out;

  char* ws = (char*)d_ws;
  u16*   wT    = (u16*)(ws + OFF_WT);
  u16*   hB    = (u16*)(ws + OFF_HB);
  u16*   qkv   = (u16*)(ws + OFF_QKV);
  u16*   ctx   = (u16*)(ws + OFF_CTX);
  float* gout0 = (float*)(ws + OFF_GOUT);
  float* gout1 = (float*)(ws + OFF_QKV);   // alias: dead during Wo/FFN2
  u16*   ff    = (u16*)(ws + OFF_FF);
  u16*   hd1   = (u16*)(ws + OFF_HD1);
  u16*   vTb   = (u16*)(ws + OFF_VT);
  u16*   relBa = (u16*)(ws + OFF_RELB);

  transpose_all<<<4640, 256, 0, stream>>>(WQ, WK, WV, WO, W1, W2, P1W, wT);
  cvt_rel_all<<<386, 256, 0, stream>>>(REL, relBa);
  input_proj<<<NTOK, 128, 0, stream>>>(X, INW, INB, hB);

  for (int l = 0; l < NLAYER; ++l) {
    const u16* wTl = wT + (size_t)l * LSTRIDE;
    // QKV fused: [8192,512] @ [512,1536]; Q,K -> qkv bf16, V -> vT transposed
    gemm_bt<<<dim3(768,1), 256, 0, stream>>>(hB, wTl, nullptr, nullptr, nullptr, qkv, vTb,
                                             8192, 1536, 512, 512, 4);
    attn_mfma<<<1024, 256, 0, stream>>>(qkv, vTb, relBa + l*17408, ctx);
    // Wo + bo, split-K=2 -> f32 partials
    gemm_bt<<<dim3(256,2), 256, 0, stream>>>(ctx, wTl + 786432, BO + l*512,
                                             gout0, gout1, nullptr, nullptr,
                                             8192, 512, 512, 256, 1);
    ln_kernel<<<NTOK, 128, 0, stream>>>(hB, gout0, gout1, LN1G + l*512, LN1B + l*512, hB);
    // FFN1: relu(h @ w1 + b1) -> bf16  (overwrites vT scratch - dead)
    gemm_bt<<<dim3(1024,1), 256, 0, stream>>>(hB, wTl + 1048576, B1 + l*2048,
                                              nullptr, nullptr, ff, nullptr,
                                              8192, 2048, 512, 512, 3);
    // FFN2: ff @ w2 + b2, split-K=2 -> f32 partials
    gemm_bt<<<dim3(256,2), 256, 0, stream>>>(ff, wTl + 2097152, B2 + l*512,
                                             gout0, gout1, nullptr, nullptr,
                                             8192, 512, 2048, 1024, 1);
    ln_kernel<<<NTOK, 128, 0, stream>>>(hB, gout0, gout1, LN2G + l*512, LN2B + l*512, hB);
  }
  ln_kernel<<<NTOK, 128, 0, stream>>>(hB, nullptr, nullptr, ONG, ONB, hB);
  // head: relu(h @ p1_w + p1_b) -> bf16 [8192][256]
  gemm_bt<<<dim3(128,1), 256, 0, stream>>>(hB, wT + P1T_OFF, P1B,
                                           nullptr, nullptr, hd1, nullptr,
                                           8192, 256, 512, 512, 3);
  head2_kernel<<<2048, 256, 0, stream>>>(hd1, P2W, P2B, out);
}

// Round 9
// 1106.313 us; speedup vs baseline: 1.2287x; 1.2287x over previous
//
#include <hip/hip_runtime.h>

typedef unsigned short u16;
typedef unsigned int   u32;
typedef short   short8  __attribute__((ext_vector_type(8)));
typedef float   floatx4 __attribute__((ext_vector_type(4)));
typedef int     intx4   __attribute__((ext_vector_type(4)));

#define NTOK 8192
#define SEQ  512
#define NLAYER 6

// ---- workspace layout (bytes) ----
#define OFF_WT   ((size_t)0)          // transposed weights (bf16), 19,005,440 u16
#define OFF_HB   ((size_t)38010880)   // h bf16   [8192][512] (residual stream)
#define OFF_QKV  ((size_t)46399488)   // qkv bf16 [8192][1536] (25.2 MB)
#define OFF_CTX  ((size_t)71565312)   // ctx bf16 [8192][512]
#define OFF_GOUT ((size_t)79953920)   // gout0 fp32 [8192][512]
#define OFF_FF   ((size_t)96731136)   // ff bf16  [8192][2048]  (33.5 MB)
#define OFF_HD1  ((size_t)130285568)  // head1 bf16 [8192][256] (4.2 MB)
// aliases:
//   gout1 (split-K partial, f32 [8192][512]) -> qkv region (dead during Wo/FFN2)
//   vT bf16 [128 bh][64][512] (8.4 MB) -> ff region (dead during attn)
//   relB_all bf16 [6][272][64] (209 KB) -> hd1 region (hd1 written only at end)
#define OFF_VT   OFF_FF
#define OFF_RELB OFF_HD1

#define LSTRIDE 3145728   // wT elems per layer: [QT;KT;VT](1536x512), WoT, w1T(2048x512), w2T(512x2048)
#define P1T_OFF 18874368  // p1T [256][512]

__device__ __forceinline__ float b2f(u16 v) { return __uint_as_float(((u32)v) << 16); }
__device__ __forceinline__ float lo16(u32 v) { return __uint_as_float(v << 16); }
__device__ __forceinline__ float hi16(u32 v) { return __uint_as_float(v & 0xffff0000u); }
__device__ __forceinline__ u16 f2b(float f) {
  u32 x = __float_as_uint(f);
  return (u16)((x + 0x7fffu + ((x >> 16) & 1u)) >> 16);
}
__device__ __forceinline__ u32 pack2(float a, float b) {
  return (u32)f2b(a) | ((u32)f2b(b) << 16);
}
__device__ __forceinline__ u32 cvtpk(float a, float b) {
  u32 r;
  asm("v_cvt_pk_bf16_f32 %0, %1, %2" : "=v"(r) : "v"(a), "v"(b));
  return r;
}

typedef __attribute__((address_space(1))) void* gas_t;
typedef __attribute__((address_space(3))) void* las_t;

// ---------------------------------------------------------------------------
// Transpose all f32 weight matrices into wT, in MFMA-FRAGMENT-PACKED layout:
// element (n,k) of logical Bt[N][K] lives at
//   (((n>>7)*(K>>5) + (k>>5))*8 + ((n>>4)&7))*512
//   + (((k>>3)&3)*16 + (n&15))*8 + (k&7)
// so fragment (nb,kc,j) is 512 contiguous u16 and lane l's short8 is at l*8:
// gemm_bt loads B operands straight from global as coalesced 1 KB reads
// (no LDS staging for B at all). Per-matrix size unchanged (N*K elems) ->
// all wT offsets including fused-QKV sub-blocks are preserved.
// ---------------------------------------------------------------------------
__global__ __launch_bounds__(256) void transpose_all(
    const float* __restrict__ Wq, const float* __restrict__ Wk,
    const float* __restrict__ Wv, const float* __restrict__ Wo,
    const float* __restrict__ w1, const float* __restrict__ w2,
    const float* __restrict__ p1, u16* __restrict__ wT)
{
  __shared__ u16 tile[64][65];
  const int tb = blockIdx.x;
  const float* src; u16* dst; int R, C, tidx;
  if (tb < 4608) {
    const int l = tb / 768, r = tb % 768;
    const size_t lofs = (size_t)l * LSTRIDE;
    if (r < 256) {
      const int m = r >> 6; tidx = r & 63; R = 512; C = 512;
      const float* bases[4] = {Wq, Wk, Wv, Wo};
      src = bases[m] + (size_t)l * 262144;
      dst = wT + lofs + (size_t)m * 262144;
    } else if (r < 512) {
      tidx = r - 256; R = 512; C = 2048;
      src = w1 + (size_t)l * 1048576; dst = wT + lofs + 1048576;
    } else {
      tidx = r - 512; R = 2048; C = 512;
      src = w2 + (size_t)l * 1048576; dst = wT + lofs + 2097152;
    }
  } else {
    tidx = tb - 4608; R = 512; C = 256;
    src = p1; dst = wT + P1T_OFF;
  }
  // src is W[R=K][C=N]; logical dst Bt[N][K] but stored fragment-packed.
  const int tcn = C >> 6;
  const int tr = tidx / tcn, tc = tidx % tcn;
  const int th = threadIdx.x;
  {
    const int lr = th >> 2, cg = (th & 3) * 16;
    const float* sp = src + (size_t)(tr*64 + lr) * C + tc*64 + cg;
    float4 f0 = *(const float4*)(sp);
    float4 f1 = *(const float4*)(sp + 4);
    float4 f2 = *(const float4*)(sp + 8);
    float4 f3 = *(const float4*)(sp + 12);
    u16* tp = &tile[lr][cg];
    tp[0]=f2b(f0.x); tp[1]=f2b(f0.y); tp[2]=f2b(f0.z); tp[3]=f2b(f0.w);
    tp[4]=f2b(f1.x); tp[5]=f2b(f1.y); tp[6]=f2b(f1.z); tp[7]=f2b(f1.w);
    tp[8]=f2b(f2.x); tp[9]=f2b(f2.y); tp[10]=f2b(f2.z); tp[11]=f2b(f2.w);
    tp[12]=f2b(f3.x); tp[13]=f2b(f3.y); tp[14]=f2b(f3.z); tp[15]=f2b(f3.w);
  }
  __syncthreads();
  {
    const int oc = th >> 2, rg = (th & 3) * 16;
    u32 wds[8];
    #pragma unroll
    for (int i = 0; i < 8; ++i)
      wds[i] = (u32)tile[rg + 2*i][oc] | ((u32)tile[rg + 2*i + 1][oc] << 16);
    const int n  = tc*64 + oc;            // N-dim index
    const int k0 = tr*64 + rg;            // K-dim index, 16-aligned
    const int nb = n >> 7, j = (n >> 4) & 7, lr = n & 15;
    const int kc = k0 >> 5, lq = (k0 >> 3) & 3;   // lq in {0,2}
    const int KC = R >> 5;
    u16* base = dst + (((((size_t)nb*KC + kc) << 3) + j) << 9);
    uint4 o0; o0.x=wds[0]; o0.y=wds[1]; o0.z=wds[2]; o0.w=wds[3];
    uint4 o1; o1.x=wds[4]; o1.y=wds[5]; o1.z=wds[6]; o1.w=wds[7];
    *(uint4*)(base + (lq*16 + lr)*8)       = o0;  // k0..k0+7
    *(uint4*)(base + ((lq+1)*16 + lr)*8)   = o1;  // k0+8..k0+15
  }
}

// ---------------------------------------------------------------------------
// h = x @ in_w + in_b + sinusoidal_pe   (K=50) -> bf16
// Each thread owns 4 consecutive d: 50 float4 loads, 2 __sincosf.
// ---------------------------------------------------------------------------
__global__ __launch_bounds__(128) void input_proj(
    const float* __restrict__ x, const float* __restrict__ w, const float* __restrict__ ib,
    u16* __restrict__ hb)
{
  const int row = blockIdx.x, t = threadIdx.x;
  const int s = row & (SEQ - 1);
  __shared__ float xs[50];
  if (t < 50) xs[t] = x[row*50 + t];
  __syncthreads();
  const int d0 = t * 4;                    // even; covers 512 with 128 threads
  float4 acc = *(const float4*)(ib + d0);
  #pragma unroll
  for (int i = 0; i < 50; ++i) {
    const float4 wv = *(const float4*)(w + i*512 + d0);
    const float xv = xs[i];
    acc.x = fmaf(xv, wv.x, acc.x);
    acc.y = fmaf(xv, wv.y, acc.y);
    acc.z = fmaf(xv, wv.z, acc.z);
    acc.w = fmaf(xv, wv.w, acc.w);
  }
  const float cexp = -0.017988946f;        // -ln(10000)/512
  const float dv0 = __expf((float)d0 * cexp);
  const float dv1 = __expf((float)(d0 + 2) * cexp);
  float s0, c0, s1, c1;
  __sincosf((float)s * dv0, &s0, &c0);
  __sincosf((float)s * dv1, &s1, &c1);
  acc.x += s0; acc.y += c0; acc.z += s1; acc.w += c1;
  u32* hp = (u32*)(hb + (size_t)row*512 + d0);
  hp[0] = pack2(acc.x, acc.y);
  hp[1] = pack2(acc.z, acc.w);
}

// ---------------------------------------------------------------------------
// C[M][N] = A[M][K] @ Bt[N][K]^T over k in [z*kLen, (z+1)*kLen)
// R6: B consumed directly from global in fragment-packed layout; only A is
// LDS-staged (double-buffered 2x16 KB). (Unchanged in R9.)
// ---------------------------------------------------------------------------
__global__ __launch_bounds__(256, 4) void gemm_bt(
    const u16* __restrict__ A, const u16* __restrict__ Bt,
    const float* __restrict__ bias,
    float* __restrict__ outF0, float* __restrict__ outF1, u16* __restrict__ outB,
    u16* __restrict__ vTout,
    const int M, const int N, const int K, const int kLen, const int flags)
{
  __shared__ __align__(16) u16 As[2][8192];   // [buf][hh*4096 + row*32 + k32]
  const int id = blockIdx.x;
  const int xcd = id & 7, rest = id >> 3;
  const int bm = (rest & 7) * 8 + xcd;
  const int bn = rest >> 3;
  const int z = blockIdx.y;
  const int kOff = z * kLen;
  const int m0 = bm << 7, n0 = bn << 7;
  const int tid = threadIdx.x;
  const int wave = tid >> 6, lane = tid & 63;
  const int wr = (wave >> 1) << 6, wc = (wave & 1) << 6;
  const int lrow = lane & 15, lquad = lane >> 4;

  floatx4 acc[4][4];
  #pragma unroll
  for (int i = 0; i < 4; ++i)
    #pragma unroll
    for (int j = 0; j < 4; ++j) { floatx4 zz = {0.f,0.f,0.f,0.f}; acc[i][j] = zz; }

  const u16* a0p = A + (size_t)m0 * K + kOff;
  const int c0 = tid, c1 = 256 + tid;
  const int ar0 = c0 >> 2, as0 = (c0 & 3) * 8;
  const int ar1 = c1 >> 2, as1 = (c1 & 3) * 8;
  const int KC = K >> 5;
  // base of this wave's B-fragment stream: (bn, kc=kOff/32, jglob=(wave&1)*4)
  const u16* bW = Bt + ((((size_t)bn*KC + (kOff >> 5)) * 8 + (wave & 1) * 4) << 9) + lane*8;

#define STAGE_A(buf, k0) do {                                                                  \
    __builtin_amdgcn_global_load_lds((gas_t)(a0p + (size_t)ar0*K + (k0) + as0),                \
                                     (las_t)(&As[buf][c0*8]), 16, 0, 0);                       \
    __builtin_amdgcn_global_load_lds((gas_t)(a0p + (size_t)ar1*K + (k0) + as1),                \
                                     (las_t)(&As[buf][c1*8]), 16, 0, 0);                       \
    __builtin_amdgcn_global_load_lds((gas_t)(a0p + (size_t)ar0*K + (k0) + 32 + as0),           \
                                     (las_t)(&As[buf][4096 + c0*8]), 16, 0, 0);                \
    __builtin_amdgcn_global_load_lds((gas_t)(a0p + (size_t)ar1*K + (k0) + 32 + as1),           \
                                     (las_t)(&As[buf][4096 + c1*8]), 16, 0, 0);                \
  } while (0)

  const int nst = kLen >> 6;
  STAGE_A(0, 0);
  __syncthreads();

  int cur = 0;
  for (int t = 0; t < nst; ++t) {
    // B fragments for this chunk, straight from global (packed layout).
    const u16* bc = bW + (size_t)(2*t) * 4096;
    short8 b0[4], b1[4];
    #pragma unroll
    for (int j = 0; j < 4; ++j) b0[j] = *(const short8*)(bc + j*512);
    if (t + 1 < nst) STAGE_A(cur ^ 1, (t + 1) * 64);
    #pragma unroll
    for (int j = 0; j < 4; ++j) b1[j] = *(const short8*)(bc + 4096 + j*512);
    // hh = 0
    {
      short8 af[4];
      #pragma unroll
      for (int i = 0; i < 4; ++i) af[i] = *(const short8*)&As[cur][(wr + i*16 + lrow)*32 + lquad*8];
      #pragma unroll
      for (int i = 0; i < 4; ++i)
        #pragma unroll
        for (int j = 0; j < 4; ++j)
          acc[i][j] = __builtin_amdgcn_mfma_f32_16x16x32_bf16(b0[j], af[i], acc[i][j], 0, 0, 0);
    }
    // hh = 1
    {
      short8 af[4];
      #pragma unroll
      for (int i = 0; i < 4; ++i) af[i] = *(const short8*)&As[cur][4096 + (wr + i*16 + lrow)*32 + lquad*8];
      #pragma unroll
      for (int i = 0; i < 4; ++i)
        #pragma unroll
        for (int j = 0; j < 4; ++j)
          acc[i][j] = __builtin_amdgcn_mfma_f32_16x16x32_bf16(b1[j], af[i], acc[i][j], 0, 0, 0);
    }
    if (t + 1 < nst) { __syncthreads(); cur ^= 1; }
  }
#undef STAGE_A

  // Swapped layout: lane owns row = m0+wr+i*16+lrow (fixed),
  //                 cols = n0+wc+j*16+lquad*4 + v (v=0..3 consecutive)
  if ((flags & 4) && n0 >= 1024) {
    // V block of QKV: write into vT[(b*8+h)*64+d][s] (bf16), scalar stores
    #pragma unroll
    for (int i = 0; i < 4; ++i) {
      const int row = m0 + wr + i*16 + lrow;
      const int bb = row >> 9, s = row & 511;
      #pragma unroll
      for (int j = 0; j < 4; ++j) {
        const int cm0 = (n0 - 1024) + wc + j*16 + lquad*4;
        #pragma unroll
        for (int v = 0; v < 4; ++v) {
          const int cm = cm0 + v;
          const int hh = cm >> 6, d = cm & 63;
          vTout[((size_t)(bb*8 + hh)*64 + d)*512 + s] = f2b(acc[i][j][v]);
        }
      }
    }
    return;
  }

  float* outF = (z == 0) ? outF0 : outF1;
  const bool hasb = ((flags & 1) != 0) && (z == 0);
  const bool dorelu = (flags & 2) != 0;
  #pragma unroll
  for (int i = 0; i < 4; ++i) {
    const int row = m0 + wr + i*16 + lrow;
    #pragma unroll
    for (int j = 0; j < 4; ++j) {
      const int colbase = n0 + wc + j*16 + lquad*4;
      float4 bv4 = make_float4(0.f, 0.f, 0.f, 0.f);
      if (hasb) bv4 = *(const float4*)(bias + colbase);
      float v0 = acc[i][j][0] + bv4.x;
      float v1 = acc[i][j][1] + bv4.y;
      float v2 = acc[i][j][2] + bv4.z;
      float v3 = acc[i][j][3] + bv4.w;
      if (dorelu) {
        v0 = fmaxf(v0, 0.f); v1 = fmaxf(v1, 0.f);
        v2 = fmaxf(v2, 0.f); v3 = fmaxf(v3, 0.f);
      }
      const size_t off = (size_t)row * N + colbase;
      if (outB) {
        uint2 o; o.x = pack2(v0, v1); o.y = pack2(v2, v3);
        *(uint2*)(outB + off) = o;
      } else {
        *(float4*)(outF + off) = make_float4(v0, v1, v2, v3);
      }
    }
  }
}

// ---------------------------------------------------------------------------
// All layers' rel_emb f32 [6][257][64] -> bf16 relB_all [6][272][64]
// ---------------------------------------------------------------------------
__global__ __launch_bounds__(256) void cvt_rel_all(
    const float* __restrict__ rel, u16* __restrict__ relB)
{
  const int i = blockIdx.x*256 + threadIdx.x;
  if (i < 6*257*64) {
    const int l = i / 16448, rem = i % 16448;
    relB[l*17408 + rem] = f2b(rel[i]);
  }
}

// ---------------------------------------------------------------------------
// MFMA flash attention, S^T / register-P version.
// R9: keep R8's 40,960 B LDS (4 blocks/CU, single-round grid) but restore V
// staging through LDS by TIME-SHARING the single 8 KB tile buffer between K
// and V within each kt iteration:
//   barrier A -> write K(kt) -> barrier B -> [prefetch K(kt+1) to regs]
//   -> QK^T -> softmax (register-only) -> barrier C -> write V(kt) from regs
//   (prefetched during prev iter's PV) -> barrier D -> [prefetch V(kt+1)]
//   -> PV.
// This fixes R8's regression: R8 read V fragments straight from global with
// lane->row stride 1024 B (16 cache lines per instruction, the R1 failure
// mode). Here both K and V reach LDS via the fully-coalesced (srow,scol)
// pattern. 4 barriers/kt instead of 2, but with 16 waves/CU the unsynced
// neighbor blocks hide the barrier stalls.
// LDS: KV 8192 (XOR swizzle byte^=(row&7)<<4, write+read) + Pr 32768
//   = 40,960 B = 160KB/4 -> all 1024 blocks resident in ONE round.
// Keeps: Pr-256 + prHi register (R8, correctness-proven), band-specialized
// bias (R7), register-P PV (R3), T5 setprio.
// ---------------------------------------------------------------------------
__global__ __launch_bounds__(256, 4) void attn_mfma(
    const u16* __restrict__ qkv, const u16* __restrict__ vT,
    const u16* __restrict__ relB, u16* __restrict__ ctx)
{
  const int id = blockIdx.x;
  const int xcd = id & 7, g = (id >> 3) & 15, qt = id >> 7;
  const int bh = xcd*16 + g;
  const int b = bh >> 3, h = bh & 7;
  const int t = threadIdx.x, w = t >> 6, lane = t & 63;
  const int lr = lane & 15, quad = lane >> 4;

  __shared__ __align__(16) u16 KV[64*64];   // time-shared K/V tile, XOR-swizzled
  __shared__ __align__(16) u16 Pr[64*256];  // bias*log2e, dd in [-128,127]

  const size_t token0 = (size_t)b*512 + qt*64;
  const int srow = t >> 2, scol = (t & 3) * 16;
  const u16* kbase = qkv + (size_t)b*512*1536 + 512 + h*64;
  const u16* vbase = vT + (size_t)bh*64*512;

  // Q fragment (needed immediately for Pr build)
  short8 af0, af1;
  {
    const u16* qp = qkv + (token0 + w*16 + lr)*1536 + h*64 + quad*8;
    af0 = *(const short8*)(qp);
    af1 = *(const short8*)(qp + 32);
  }

  // prefetch kt=0 K and V into regs; latency hides under Pr build below
  uint4 kr0, kr1, vr0, vr1;
  {
    const u16* kp = kbase + (size_t)srow*1536 + scol;
    kr0 = *(const uint4*)kp; kr1 = *(const uint4*)(kp + 8);
    const u16* vp = vbase + (size_t)srow*512 + scol;
    vr0 = *(const uint4*)vp; vr1 = *(const uint4*)(vp + 8);
  }

  // Pr[q][j] = (Q[q] . relB[j]) * log2(e), j in [0,256) -> dd = j-128.
  // Rows w*16+quad*4+r are wave-private; read side uses rows w*16+lr ->
  // same 16-row slab, same wave -> in-order DS pipe, no barrier (R3-proven).
  #pragma unroll 4
  for (int nt = 0; nt < 16; ++nt) {
    const u16* rp = relB + (nt*16 + lr)*64 + quad*8;
    short8 rb0 = *(const short8*)(rp);
    short8 rb1 = *(const short8*)(rp + 32);
    floatx4 c = {0.f,0.f,0.f,0.f};
    c = __builtin_amdgcn_mfma_f32_16x16x32_bf16(af0, rb0, c, 0, 0, 0);
    c = __builtin_amdgcn_mfma_f32_16x16x32_bf16(af1, rb1, c, 0, 0, 0);
    #pragma unroll
    for (int r = 0; r < 4; ++r)
      Pr[(w*16 + quad*4 + r)*256 + nt*16 + lr] = f2b(c[r] * 1.44269504f);
  }
  // boundary column j=256 (dd=+128): compute, stash via KV, read back to reg.
  {
    const u16* rp = relB + (256 + lr)*64 + quad*8;   // lr>0 rows are pad; results discarded
    short8 rb0 = *(const short8*)(rp);
    short8 rb1 = *(const short8*)(rp + 32);
    floatx4 c = {0.f,0.f,0.f,0.f};
    c = __builtin_amdgcn_mfma_f32_16x16x32_bf16(af0, rb0, c, 0, 0, 0);
    c = __builtin_amdgcn_mfma_f32_16x16x32_bf16(af1, rb1, c, 0, 0, 0);
    if (lr == 0) {
      #pragma unroll
      for (int r = 0; r < 4; ++r)
        KV[w*16 + quad*4 + r] = f2b(c[r] * 1.44269504f);
    }
  }
  const float prHi = b2f(KV[w*16 + lr]);        // dd = +128 (same-wave slab)
  const float prLo = b2f(Pr[(w*16 + lr)*256]);  // dd = -128

  floatx4 oacc[4];
  float lacc = 0.f;
  #pragma unroll
  for (int n = 0; n < 4; ++n) { floatx4 zz = {0.f,0.f,0.f,0.f}; oacc[n] = zz; }

  const int qglob = qt*64 + w*16 + lr;          // this lane's q (global)
  const int prbase = (w*16 + lr)*256 + 128;     // Pr row base + offset
  const int swzW = (srow & 7) << 4;             // staging-side swizzle
  char* kvb = (char*)KV;

  for (int kt = 0; kt < 8; ++kt) {
    __syncthreads();  // A: prev iter's PV reads of KV done
    *(uint4*)(kvb + ((srow*128 + scol*2) ^ swzW))      = kr0;
    *(uint4*)(kvb + ((srow*128 + scol*2 + 16) ^ swzW)) = kr1;
    __syncthreads();  // B: K visible

    // prefetch NEXT tile's K (consumed at next iter's barrier-A write)
    if (kt < 7) {
      const u16* kp = kbase + (size_t)((kt+1)*64 + srow)*1536 + scol;
      kr0 = *(const uint4*)kp; kr1 = *(const uint4*)(kp + 8);
    }

    // S^T = K . Q^T  (lane: col=lr -> q fixed, row=quad*4+r -> k-local)
    floatx4 s4[4];
    __builtin_amdgcn_s_setprio(1);
    #pragma unroll
    for (int nt = 0; nt < 4; ++nt) {
      const int row = nt*16 + lr;
      const char* kbp = (const char*)KV + row*128;
      const int swz = (lr & 7) << 4;
      short8 kb0 = *(const short8*)(kbp + ((quad*16) ^ swz));
      short8 kb1 = *(const short8*)(kbp + ((64 + quad*16) ^ swz));
      floatx4 c = {0.f,0.f,0.f,0.f};
      c = __builtin_amdgcn_mfma_f32_16x16x32_bf16(kb0, af0, c, 0, 0, 0);
      c = __builtin_amdgcn_mfma_f32_16x16x32_bf16(kb1, af1, c, 0, 0, 0);
      s4[nt] = c;
    }
    __builtin_amdgcn_s_setprio(0);

    // P = exp2(S*0.125*log2e + bias), packed to bf16 pairs (register-only,
    // no KV dependency -> runs before barrier C).
    const int tmin = kt*64 - (qt*64 + w*16 + 15);   // min dd over wave tile
    const int tmax = tmin + 78;                     // max dd
    u32 wq[4][2];
    const int kq = kt*64 + quad*4 - qglob;
    if (tmin >= 128 || tmax <= -128) {
      // fully clamped: bias constant per lane
      const float pc = (tmin >= 128) ? prHi : prLo;
      #pragma unroll
      for (int nt = 0; nt < 4; ++nt) {
        float p[4];
        #pragma unroll
        for (int r = 0; r < 4; ++r)
          p[r] = exp2f(fmaf(s4[nt][r], 0.18033688f, pc));
        lacc += (p[0] + p[1]) + (p[2] + p[3]);
        wq[nt][0] = cvtpk(p[0], p[1]);
        wq[nt][1] = cvtpk(p[2], p[3]);
      }
    } else if (tmin >= -128 && tmax <= 127) {
      // interior: direct table read, no clamp
      #pragma unroll
      for (int nt = 0; nt < 4; ++nt) {
        const int dbase = kq + nt*16;
        float p[4];
        #pragma unroll
        for (int r = 0; r < 4; ++r)
          p[r] = exp2f(fmaf(s4[nt][r], 0.18033688f, b2f(Pr[prbase + dbase + r])));
        lacc += (p[0] + p[1]) + (p[2] + p[3]);
        wq[nt][0] = cvtpk(p[0], p[1]);
        wq[nt][1] = cvtpk(p[2], p[3]);
      }
    } else {
      // partial: clamped gather; dd>=128 -> prHi register
      #pragma unroll
      for (int nt = 0; nt < 4; ++nt) {
        const int dbase = kq + nt*16;
        float p[4];
        #pragma unroll
        for (int r = 0; r < 4; ++r) {
          const int dd = dbase + r;
          int di = dd < -128 ? -128 : (dd > 127 ? 127 : dd);
          const float bias = (dd >= 128) ? prHi : b2f(Pr[prbase + di]);
          p[r] = exp2f(fmaf(s4[nt][r], 0.18033688f, bias));
        }
        lacc += (p[0] + p[1]) + (p[2] + p[3]);
        wq[nt][0] = cvtpk(p[0], p[1]);
        wq[nt][1] = cvtpk(p[2], p[3]);
      }
    }

    // PV B-fragments assembled in registers
    intx4 pw0; pw0.x = (int)wq[0][0]; pw0.y = (int)wq[0][1];
               pw0.z = (int)wq[1][0]; pw0.w = (int)wq[1][1];
    intx4 pw1; pw1.x = (int)wq[2][0]; pw1.y = (int)wq[2][1];
               pw1.z = (int)wq[3][0]; pw1.w = (int)wq[3][1];
    const short8 pf0 = __builtin_bit_cast(short8, pw0);
    const short8 pf1 = __builtin_bit_cast(short8, pw1);

    __syncthreads();  // C: all waves done reading KV as K
    *(uint4*)(kvb + ((srow*128 + scol*2) ^ swzW))      = vr0;
    *(uint4*)(kvb + ((srow*128 + scol*2 + 16) ^ swzW)) = vr1;
    __syncthreads();  // D: V visible

    // prefetch NEXT tile's V (consumed at next iter's barrier-C write)
    if (kt < 7) {
      const u16* vp = vbase + (size_t)srow*512 + (kt+1)*64 + scol;
      vr0 = *(const uint4*)vp; vr1 = *(const uint4*)(vp + 8);
    }

    // O += V x P : A-frag vb[row=d][kk] = V^T[d][sigma(kk)];
    // sigma(kk = quad*8+j) = (j>>2)*16 + quad*4 + (j&3)  (+32 for pf1 half)
    __builtin_amdgcn_s_setprio(1);
    #pragma unroll
    for (int nd = 0; nd < 4; ++nd) {
      const int row = nd*16 + lr;
      const char* vbp = (const char*)KV + row*128;
      const int swz = (lr & 7) << 4;
      uint2 a0 = *(const uint2*)(vbp + ((quad*8) ^ swz));
      uint2 a1 = *(const uint2*)(vbp + ((32 + quad*8) ^ swz));
      uint2 a2 = *(const uint2*)(vbp + ((64 + quad*8) ^ swz));
      uint2 a3 = *(const uint2*)(vbp + ((96 + quad*8) ^ swz));
      intx4 v0; v0.x = (int)a0.x; v0.y = (int)a0.y; v0.z = (int)a1.x; v0.w = (int)a1.y;
      intx4 v1; v1.x = (int)a2.x; v1.y = (int)a2.y; v1.z = (int)a3.x; v1.w = (int)a3.y;
      const short8 vb0 = __builtin_bit_cast(short8, v0);
      const short8 vb1 = __builtin_bit_cast(short8, v1);
      oacc[nd] = __builtin_amdgcn_mfma_f32_16x16x32_bf16(vb0, pf0, oacc[nd], 0, 0, 0);
      oacc[nd] = __builtin_amdgcn_mfma_f32_16x16x32_bf16(vb1, pf1, oacc[nd], 0, 0, 0);
    }
    __builtin_amdgcn_s_setprio(0);
  }

  // cross-quad denominator reduce (q = lr is shared by the 4 quads)
  lacc += __shfl_xor(lacc, 16);
  lacc += __shfl_xor(lacc, 32);

  // epilogue: q = lr (fixed per lane); lane writes d = nd*16 + quad*4 + v
  {
    const float inv = 1.f / lacc;
    u16* cp = ctx + (token0 + w*16 + lr)*512 + h*64;
    #pragma unroll
    for (int nd = 0; nd < 4; ++nd) {
      const int d = nd*16 + quad*4;
      uint2 o;
      o.x = pack2(oacc[nd][0]*inv, oacc[nd][1]*inv);
      o.y = pack2(oacc[nd][2]*inv, oacc[nd][3]*inv);
      *(uint2*)(cp + d) = o;
    }
  }
}

// ---------------------------------------------------------------------------
// LayerNorm over D=512: h = LN(b2f(resB) (+ add0) (+ add1)) * g + b -> hb
// ---------------------------------------------------------------------------
__global__ __launch_bounds__(128) void ln_kernel(
    const u16* __restrict__ resB, const float* __restrict__ add0,
    const float* __restrict__ add1,
    const float* __restrict__ g, const float* __restrict__ be,
    u16* __restrict__ hb)
{
  const int row = blockIdx.x, t = threadIdx.x;
  const size_t base = (size_t)row * 512;
  const u32 r0 = *(const u32*)(resB + base + t*4);
  const u32 r1 = *(const u32*)(resB + base + t*4 + 2);
  float x0 = lo16(r0), x1 = hi16(r0), x2 = lo16(r1), x3 = hi16(r1);
  if (add0) {
    const float4 a = *(const float4*)(add0 + base + t*4);
    x0 += a.x; x1 += a.y; x2 += a.z; x3 += a.w;
  }
  if (add1) {
    const float4 a = *(const float4*)(add1 + base + t*4);
    x0 += a.x; x1 += a.y; x2 += a.z; x3 += a.w;
  }
  float s = x0 + x1 + x2 + x3;
  #pragma unroll
  for (int off = 32; off > 0; off >>= 1) s += __shfl_down(s, off);
  __shared__ float red[2];
  const int wv = t >> 6, ln = t & 63;
  if (ln == 0) red[wv] = s;
  __syncthreads();
  const float mean = (red[0] + red[1]) * (1.f/512.f);
  const float dx0 = x0-mean, dx1 = x1-mean, dx2 = x2-mean, dx3 = x3-mean;
  float vs = dx0*dx0 + dx1*dx1 + dx2*dx2 + dx3*dx3;
  __syncthreads();
  #pragma unroll
  for (int off = 32; off > 0; off >>= 1) vs += __shfl_down(vs, off);
  if (ln == 0) red[wv] = vs;
  __syncthreads();
  const float var = (red[0] + red[1]) * (1.f/512.f);
  const float inv = 1.f / sqrtf(var + 1e-5f);
  const float4 gv = *(const float4*)(g + t*4);
  const float4 bv = *(const float4*)(be + t*4);
  const float y0 = dx0*inv*gv.x + bv.x;
  const float y1 = dx1*inv*gv.y + bv.y;
  const float y2 = dx2*inv*gv.z + bv.z;
  const float y3 = dx3*inv*gv.w + bv.w;
  u32* hp = (u32*)(hb + base + t*4);
  hp[0] = pack2(y0, y1); hp[1] = pack2(y2, y3);
}

// ---------------------------------------------------------------------------
// out[row] = hd1[row][:] . p2_w + p2_b   (256-dot, one wave per row), f32 out
// ---------------------------------------------------------------------------
__global__ __launch_bounds__(256) void head2_kernel(
    const u16* __restrict__ hd1, const float* __restrict__ p2w,
    const float* __restrict__ p2b, float* __restrict__ out)
{
  const int wv = threadIdx.x >> 6, ln = threadIdx.x & 63;
  const int row = blockIdx.x * 4 + wv;
  const u16* hp = hd1 + (size_t)row * 256 + ln*4;
  const u32 h0 = *(const u32*)hp, h1 = *(const u32*)(hp + 2);
  const float4 w = *(const float4*)(p2w + ln*4);
  float acc = lo16(h0)*w.x + hi16(h0)*w.y + lo16(h1)*w.z + hi16(h1)*w.w;
  #pragma unroll
  for (int off = 1; off < 64; off <<= 1) acc += __shfl_xor(acc, off);
  if (ln == 0) out[row] = acc + p2b[0];
}

// ---------------------------------------------------------------------------
extern "C" void kernel_launch(void* const* d_in, const int* in_sizes, int n_in,
                              void* d_out, int out_size, void* d_ws, size_t ws_size,
                              hipStream_t stream) {
  (void)in_sizes; (void)n_in; (void)out_size; (void)ws_size;
  const float* X    = (const float*)d_in[0];
  const float* INW  = (const float*)d_in[1];
  const float* INB  = (const float*)d_in[2];
  const float* WQ   = (const float*)d_in[3];
  const float* WK   = (const float*)d_in[4];
  const float* WV   = (const float*)d_in[5];
  const float* WO   = (const float*)d_in[6];
  const float* BO   = (const float*)d_in[7];
  const float* REL  = (const float*)d_in[8];
  const float* W1   = (const float*)d_in[9];
  const float* B1   = (const float*)d_in[10];
  const float* W2   = (const float*)d_in[11];
  const float* B2   = (const float*)d_in[12];
  const float* LN1G = (const float*)d_in[13];
  const float* LN1B = (const float*)d_in[14];
  const float* LN2G = (const float*)d_in[15];
  const float* LN2B = (const float*)d_in[16];
  const float* ONG  = (const float*)d_in[17];
  const float* ONB  = (const float*)d_in[18];
  const float* P1W  = (const float*)d_in[19];
  const float* P1B  = (const float*)d_in[20];
  const float* P2W  = (const float*)d_in[21];
  const float* P2B  = (const float*)d_in[22];
  float* out = (float*)d_out;

  char* ws = (char*)d_ws;
  u16*   wT    = (u16*)(ws + OFF_WT);
  u16*   hB    = (u16*)(ws + OFF_HB);
  u16*   qkv   = (u16*)(ws + OFF_QKV);
  u16*   ctx   = (u16*)(ws + OFF_CTX);
  float* gout0 = (float*)(ws + OFF_GOUT);
  float* gout1 = (float*)(ws + OFF_QKV);   // alias: dead during Wo/FFN2
  u16*   ff    = (u16*)(ws + OFF_FF);
  u16*   hd1   = (u16*)(ws + OFF_HD1);
  u16*   vTb   = (u16*)(ws + OFF_VT);
  u16*   relBa = (u16*)(ws + OFF_RELB);

  transpose_all<<<4640, 256, 0, stream>>>(WQ, WK, WV, WO, W1, W2, P1W, wT);
  cvt_rel_all<<<386, 256, 0, stream>>>(REL, relBa);
  input_proj<<<NTOK, 128, 0, stream>>>(X, INW, INB, hB);

  for (int l = 0; l < NLAYER; ++l) {
    const u16* wTl = wT + (size_t)l * LSTRIDE;
    // QKV fused: [8192,512] @ [512,1536]; Q,K -> qkv bf16, V -> vT transposed
    gemm_bt<<<dim3(768,1), 256, 0, stream>>>(hB, wTl, nullptr, nullptr, nullptr, qkv, vTb,
                                             8192, 1536, 512, 512, 4);
    attn_mfma<<<1024, 256, 0, stream>>>(qkv, vTb, relBa + l*17408, ctx);
    // Wo + bo, split-K=2 -> f32 partials
    gemm_bt<<<dim3(256,2), 256, 0, stream>>>(ctx, wTl + 786432, BO + l*512,
                                             gout0, gout1, nullptr, nullptr,
                                             8192, 512, 512, 256, 1);
    ln_kernel<<<NTOK, 128, 0, stream>>>(hB, gout0, gout1, LN1G + l*512, LN1B + l*512, hB);
    // FFN1: relu(h @ w1 + b1) -> bf16  (overwrites vT scratch - dead)
    gemm_bt<<<dim3(1024,1), 256, 0, stream>>>(hB, wTl + 1048576, B1 + l*2048,
                                              nullptr, nullptr, ff, nullptr,
                                              8192, 2048, 512, 512, 3);
    // FFN2: ff @ w2 + b2, split-K=2 -> f32 partials
    gemm_bt<<<dim3(256,2), 256, 0, stream>>>(ff, wTl + 2097152, B2 + l*512,
                                             gout0, gout1, nullptr, nullptr,
                                             8192, 512, 2048, 1024, 1);
    ln_kernel<<<NTOK, 128, 0, stream>>>(hB, gout0, gout1, LN2G + l*512, LN2B + l*512, hB);
  }
  ln_kernel<<<NTOK, 128, 0, stream>>>(hB, nullptr, nullptr, ONG, ONB, hB);
  // head: relu(h @ p1_w + p1_b) -> bf16 [8192][256]
  gemm_bt<<<dim3(128,1), 256, 0, stream>>>(hB, wT + P1T_OFF, P1B,
                                           nullptr, nullptr, hd1, nullptr,
                                           8192, 256, 512, 512, 3);
  head2_kernel<<<2048, 256, 0, stream>>>(hd1, P2W, P2B, out);
}

// Round 11
// 1079.146 us; speedup vs baseline: 1.2596x; 1.0252x over previous
//
#include <hip/hip_runtime.h>

typedef unsigned short u16;
typedef unsigned int   u32;
typedef short   short8  __attribute__((ext_vector_type(8)));
typedef float   floatx4 __attribute__((ext_vector_type(4)));
typedef int     intx4   __attribute__((ext_vector_type(4)));

#define NTOK 8192
#define SEQ  512
#define NLAYER 6

// ---- workspace layout (bytes) ----
#define OFF_WT   ((size_t)0)          // transposed weights (bf16), 19,005,440 u16
#define OFF_HB   ((size_t)38010880)   // h bf16   [8192][512] (residual stream)
#define OFF_QKV  ((size_t)46399488)   // qkv bf16 [8192][1536] (25.2 MB)
#define OFF_CTX  ((size_t)71565312)   // ctx bf16 [8192][512]
#define OFF_GOUT ((size_t)79953920)   // gout0 fp32 [8192][512]
#define OFF_FF   ((size_t)96731136)   // ff bf16  [8192][2048]  (33.5 MB)
#define OFF_HD1  ((size_t)130285568)  // head1 bf16 [8192][256] (4.2 MB)
// aliases:
//   gout1 (split-K partial, f32 [8192][512]) -> qkv region (dead during Wo/FFN2)
//   vT bf16 [128 bh][64][512] (8.4 MB) -> ff region (dead during attn)
//   relB_all bf16 [6][272][64] (209 KB) -> hd1 region (hd1 written only at end)
#define OFF_VT   OFF_FF
#define OFF_RELB OFF_HD1

#define LSTRIDE 3145728   // wT elems per layer: [QT;KT;VT](1536x512), WoT, w1T(2048x512), w2T(512x2048)
#define P1T_OFF 18874368  // p1T [256][512]

__device__ __forceinline__ float b2f(u16 v) { return __uint_as_float(((u32)v) << 16); }
__device__ __forceinline__ float lo16(u32 v) { return __uint_as_float(v << 16); }
__device__ __forceinline__ float hi16(u32 v) { return __uint_as_float(v & 0xffff0000u); }
__device__ __forceinline__ u16 f2b(float f) {
  u32 x = __float_as_uint(f);
  return (u16)((x + 0x7fffu + ((x >> 16) & 1u)) >> 16);
}
__device__ __forceinline__ u32 pack2(float a, float b) {
  return (u32)f2b(a) | ((u32)f2b(b) << 16);
}
__device__ __forceinline__ u32 cvtpk(float a, float b) {
  u32 r;
  asm("v_cvt_pk_bf16_f32 %0, %1, %2" : "=v"(r) : "v"(a), "v"(b));
  return r;
}

typedef __attribute__((address_space(1))) void* gas_t;
typedef __attribute__((address_space(3))) void* las_t;

// ---------------------------------------------------------------------------
// Transpose all f32 weight matrices into wT, in MFMA-FRAGMENT-PACKED layout:
// element (n,k) of logical Bt[N][K] lives at
//   (((n>>7)*(K>>5) + (k>>5))*8 + ((n>>4)&7))*512
//   + (((k>>3)&3)*16 + (n&15))*8 + (k&7)
// so fragment (nb,kc,j) is 512 contiguous u16 and lane l's short8 is at l*8:
// gemm_bt loads B operands straight from global as coalesced 1 KB reads.
// ---------------------------------------------------------------------------
__global__ __launch_bounds__(256) void transpose_all(
    const float* __restrict__ Wq, const float* __restrict__ Wk,
    const float* __restrict__ Wv, const float* __restrict__ Wo,
    const float* __restrict__ w1, const float* __restrict__ w2,
    const float* __restrict__ p1, u16* __restrict__ wT)
{
  __shared__ u16 tile[64][65];
  const int tb = blockIdx.x;
  const float* src; u16* dst; int R, C, tidx;
  if (tb < 4608) {
    const int l = tb / 768, r = tb % 768;
    const size_t lofs = (size_t)l * LSTRIDE;
    if (r < 256) {
      const int m = r >> 6; tidx = r & 63; R = 512; C = 512;
      const float* bases[4] = {Wq, Wk, Wv, Wo};
      src = bases[m] + (size_t)l * 262144;
      dst = wT + lofs + (size_t)m * 262144;
    } else if (r < 512) {
      tidx = r - 256; R = 512; C = 2048;
      src = w1 + (size_t)l * 1048576; dst = wT + lofs + 1048576;
    } else {
      tidx = r - 512; R = 2048; C = 512;
      src = w2 + (size_t)l * 1048576; dst = wT + lofs + 2097152;
    }
  } else {
    tidx = tb - 4608; R = 512; C = 256;
    src = p1; dst = wT + P1T_OFF;
  }
  // src is W[R=K][C=N]; logical dst Bt[N][K] but stored fragment-packed.
  const int tcn = C >> 6;
  const int tr = tidx / tcn, tc = tidx % tcn;
  const int th = threadIdx.x;
  {
    const int lr = th >> 2, cg = (th & 3) * 16;
    const float* sp = src + (size_t)(tr*64 + lr) * C + tc*64 + cg;
    float4 f0 = *(const float4*)(sp);
    float4 f1 = *(const float4*)(sp + 4);
    float4 f2 = *(const float4*)(sp + 8);
    float4 f3 = *(const float4*)(sp + 12);
    u16* tp = &tile[lr][cg];
    tp[0]=f2b(f0.x); tp[1]=f2b(f0.y); tp[2]=f2b(f0.z); tp[3]=f2b(f0.w);
    tp[4]=f2b(f1.x); tp[5]=f2b(f1.y); tp[6]=f2b(f1.z); tp[7]=f2b(f1.w);
    tp[8]=f2b(f2.x); tp[9]=f2b(f2.y); tp[10]=f2b(f2.z); tp[11]=f2b(f2.w);
    tp[12]=f2b(f3.x); tp[13]=f2b(f3.y); tp[14]=f2b(f3.z); tp[15]=f2b(f3.w);
  }
  __syncthreads();
  {
    const int oc = th >> 2, rg = (th & 3) * 16;
    u32 wds[8];
    #pragma unroll
    for (int i = 0; i < 8; ++i)
      wds[i] = (u32)tile[rg + 2*i][oc] | ((u32)tile[rg + 2*i + 1][oc] << 16);
    const int n  = tc*64 + oc;            // N-dim index
    const int k0 = tr*64 + rg;            // K-dim index, 16-aligned
    const int nb = n >> 7, j = (n >> 4) & 7, lr = n & 15;
    const int kc = k0 >> 5, lq = (k0 >> 3) & 3;   // lq in {0,2}
    const int KC = R >> 5;
    u16* base = dst + (((((size_t)nb*KC + kc) << 3) + j) << 9);
    uint4 o0; o0.x=wds[0]; o0.y=wds[1]; o0.z=wds[2]; o0.w=wds[3];
    uint4 o1; o1.x=wds[4]; o1.y=wds[5]; o1.z=wds[6]; o1.w=wds[7];
    *(uint4*)(base + (lq*16 + lr)*8)       = o0;  // k0..k0+7
    *(uint4*)(base + ((lq+1)*16 + lr)*8)   = o1;  // k0+8..k0+15
  }
}

// ---------------------------------------------------------------------------
// h = x @ in_w + in_b + sinusoidal_pe   (K=50) -> bf16
// Each thread owns 4 consecutive d: 50 float4 loads, 2 __sincosf.
// ---------------------------------------------------------------------------
__global__ __launch_bounds__(128) void input_proj(
    const float* __restrict__ x, const float* __restrict__ w, const float* __restrict__ ib,
    u16* __restrict__ hb)
{
  const int row = blockIdx.x, t = threadIdx.x;
  const int s = row & (SEQ - 1);
  __shared__ float xs[50];
  if (t < 50) xs[t] = x[row*50 + t];
  __syncthreads();
  const int d0 = t * 4;                    // even; covers 512 with 128 threads
  float4 acc = *(const float4*)(ib + d0);
  #pragma unroll
  for (int i = 0; i < 50; ++i) {
    const float4 wv = *(const float4*)(w + i*512 + d0);
    const float xv = xs[i];
    acc.x = fmaf(xv, wv.x, acc.x);
    acc.y = fmaf(xv, wv.y, acc.y);
    acc.z = fmaf(xv, wv.z, acc.z);
    acc.w = fmaf(xv, wv.w, acc.w);
  }
  const float cexp = -0.017988946f;        // -ln(10000)/512
  const float dv0 = __expf((float)d0 * cexp);
  const float dv1 = __expf((float)(d0 + 2) * cexp);
  float s0, c0, s1, c1;
  __sincosf((float)s * dv0, &s0, &c0);
  __sincosf((float)s * dv1, &s1, &c1);
  acc.x += s0; acc.y += c0; acc.z += s1; acc.w += c1;
  u32* hp = (u32*)(hb + (size_t)row*512 + d0);
  hp[0] = pack2(acc.x, acc.y);
  hp[1] = pack2(acc.z, acc.w);
}

// ---------------------------------------------------------------------------
// C[M][N] = A[M][K] @ Bt[N][K]^T over k in [z*kLen, (z+1)*kLen)
// R6: B consumed directly from global in fragment-packed layout; only A is
// LDS-staged (double-buffered 2x16 KB).
// ---------------------------------------------------------------------------
__global__ __launch_bounds__(256, 4) void gemm_bt(
    const u16* __restrict__ A, const u16* __restrict__ Bt,
    const float* __restrict__ bias,
    float* __restrict__ outF0, float* __restrict__ outF1, u16* __restrict__ outB,
    u16* __restrict__ vTout,
    const int M, const int N, const int K, const int kLen, const int flags)
{
  __shared__ __align__(16) u16 As[2][8192];   // [buf][hh*4096 + row*32 + k32]
  const int id = blockIdx.x;
  const int xcd = id & 7, rest = id >> 3;
  const int bm = (rest & 7) * 8 + xcd;
  const int bn = rest >> 3;
  const int z = blockIdx.y;
  const int kOff = z * kLen;
  const int m0 = bm << 7, n0 = bn << 7;
  const int tid = threadIdx.x;
  const int wave = tid >> 6, lane = tid & 63;
  const int wr = (wave >> 1) << 6, wc = (wave & 1) << 6;
  const int lrow = lane & 15, lquad = lane >> 4;

  floatx4 acc[4][4];
  #pragma unroll
  for (int i = 0; i < 4; ++i)
    #pragma unroll
    for (int j = 0; j < 4; ++j) { floatx4 zz = {0.f,0.f,0.f,0.f}; acc[i][j] = zz; }

  const u16* a0p = A + (size_t)m0 * K + kOff;
  const int c0 = tid, c1 = 256 + tid;
  const int ar0 = c0 >> 2, as0 = (c0 & 3) * 8;
  const int ar1 = c1 >> 2, as1 = (c1 & 3) * 8;
  const int KC = K >> 5;
  // base of this wave's B-fragment stream: (bn, kc=kOff/32, jglob=(wave&1)*4)
  const u16* bW = Bt + ((((size_t)bn*KC + (kOff >> 5)) * 8 + (wave & 1) * 4) << 9) + lane*8;

#define STAGE_A(buf, k0) do {                                                                  \
    __builtin_amdgcn_global_load_lds((gas_t)(a0p + (size_t)ar0*K + (k0) + as0),                \
                                     (las_t)(&As[buf][c0*8]), 16, 0, 0);                       \
    __builtin_amdgcn_global_load_lds((gas_t)(a0p + (size_t)ar1*K + (k0) + as1),                \
                                     (las_t)(&As[buf][c1*8]), 16, 0, 0);                       \
    __builtin_amdgcn_global_load_lds((gas_t)(a0p + (size_t)ar0*K + (k0) + 32 + as0),           \
                                     (las_t)(&As[buf][4096 + c0*8]), 16, 0, 0);                \
    __builtin_amdgcn_global_load_lds((gas_t)(a0p + (size_t)ar1*K + (k0) + 32 + as1),           \
                                     (las_t)(&As[buf][4096 + c1*8]), 16, 0, 0);                \
  } while (0)

  const int nst = kLen >> 6;
  STAGE_A(0, 0);
  __syncthreads();

  int cur = 0;
  for (int t = 0; t < nst; ++t) {
    // B fragments for this chunk, straight from global (packed layout).
    const u16* bc = bW + (size_t)(2*t) * 4096;
    short8 b0[4], b1[4];
    #pragma unroll
    for (int j = 0; j < 4; ++j) b0[j] = *(const short8*)(bc + j*512);
    if (t + 1 < nst) STAGE_A(cur ^ 1, (t + 1) * 64);
    #pragma unroll
    for (int j = 0; j < 4; ++j) b1[j] = *(const short8*)(bc + 4096 + j*512);
    // hh = 0
    {
      short8 af[4];
      #pragma unroll
      for (int i = 0; i < 4; ++i) af[i] = *(const short8*)&As[cur][(wr + i*16 + lrow)*32 + lquad*8];
      #pragma unroll
      for (int i = 0; i < 4; ++i)
        #pragma unroll
        for (int j = 0; j < 4; ++j)
          acc[i][j] = __builtin_amdgcn_mfma_f32_16x16x32_bf16(b0[j], af[i], acc[i][j], 0, 0, 0);
    }
    // hh = 1
    {
      short8 af[4];
      #pragma unroll
      for (int i = 0; i < 4; ++i) af[i] = *(const short8*)&As[cur][4096 + (wr + i*16 + lrow)*32 + lquad*8];
      #pragma unroll
      for (int i = 0; i < 4; ++i)
        #pragma unroll
        for (int j = 0; j < 4; ++j)
          acc[i][j] = __builtin_amdgcn_mfma_f32_16x16x32_bf16(b1[j], af[i], acc[i][j], 0, 0, 0);
    }
    if (t + 1 < nst) { __syncthreads(); cur ^= 1; }
  }
#undef STAGE_A

  // Swapped layout: lane owns row = m0+wr+i*16+lrow (fixed),
  //                 cols = n0+wc+j*16+lquad*4 + v (v=0..3 consecutive)
  if ((flags & 4) && n0 >= 1024) {
    // V block of QKV: write into vT[(b*8+h)*64+d][s] (bf16), scalar stores
    #pragma unroll
    for (int i = 0; i < 4; ++i) {
      const int row = m0 + wr + i*16 + lrow;
      const int bb = row >> 9, s = row & 511;
      #pragma unroll
      for (int j = 0; j < 4; ++j) {
        const int cm0 = (n0 - 1024) + wc + j*16 + lquad*4;
        #pragma unroll
        for (int v = 0; v < 4; ++v) {
          const int cm = cm0 + v;
          const int hh = cm >> 6, d = cm & 63;
          vTout[((size_t)(bb*8 + hh)*64 + d)*512 + s] = f2b(acc[i][j][v]);
        }
      }
    }
    return;
  }

  float* outF = (z == 0) ? outF0 : outF1;
  const bool hasb = ((flags & 1) != 0) && (z == 0);
  const bool dorelu = (flags & 2) != 0;
  #pragma unroll
  for (int i = 0; i < 4; ++i) {
    const int row = m0 + wr + i*16 + lrow;
    #pragma unroll
    for (int j = 0; j < 4; ++j) {
      const int colbase = n0 + wc + j*16 + lquad*4;
      float4 bv4 = make_float4(0.f, 0.f, 0.f, 0.f);
      if (hasb) bv4 = *(const float4*)(bias + colbase);
      float v0 = acc[i][j][0] + bv4.x;
      float v1 = acc[i][j][1] + bv4.y;
      float v2 = acc[i][j][2] + bv4.z;
      float v3 = acc[i][j][3] + bv4.w;
      if (dorelu) {
        v0 = fmaxf(v0, 0.f); v1 = fmaxf(v1, 0.f);
        v2 = fmaxf(v2, 0.f); v3 = fmaxf(v3, 0.f);
      }
      const size_t off = (size_t)row * N + colbase;
      if (outB) {
        uint2 o; o.x = pack2(v0, v1); o.y = pack2(v2, v3);
        *(uint2*)(outB + off) = o;
      } else {
        *(float4*)(outF + off) = make_float4(v0, v1, v2, v3);
      }
    }
  }
}

// ---------------------------------------------------------------------------
// All layers' rel_emb f32 [6][257][64] -> bf16 relB_all [6][272][64]
// ---------------------------------------------------------------------------
__global__ __launch_bounds__(256) void cvt_rel_all(
    const float* __restrict__ rel, u16* __restrict__ relB)
{
  const int i = blockIdx.x*256 + threadIdx.x;
  if (i < 6*257*64) {
    const int l = i / 16448, rem = i % 16448;
    relB[l*17408 + rem] = f2b(rel[i]);
  }
}

// ---------------------------------------------------------------------------
// MFMA flash attention, S^T / register-P version (EXACT R7 structure —
// measured 40.6 us, the empirical optimum; R8/R9 occupancy pushes both
// regressed: attn is barrier/serial-chain bound, not occupancy bound).
// Band-specialized rel-bias (R7), register-P PV (R3), T14 K/V reg-prefetch,
// T5 setprio. LDS: Ks 9216 + Vs 9216 + Pr 64*274*2=35072 -> 3 blocks/CU.
// ---------------------------------------------------------------------------
__global__ __launch_bounds__(256, 3) void attn_mfma(
    const u16* __restrict__ qkv, const u16* __restrict__ vT,
    const u16* __restrict__ relB, u16* __restrict__ ctx)
{
  const int id = blockIdx.x;
  const int xcd = id & 7, g = (id >> 3) & 15, qt = id >> 7;
  const int bh = xcd*16 + g;
  const int b = bh >> 3, h = bh & 7;
  const int t = threadIdx.x, w = t >> 6, lane = t & 63;
  const int lr = lane & 15, quad = lane >> 4;

  __shared__ __align__(16) u16 Ks[64*72];
  __shared__ __align__(16) u16 Vs[64*72];
  __shared__ __align__(16) u16 Pr[64*274];  // rel-bias table (pre-scaled log2e)

  const size_t token0 = (size_t)b*512 + qt*64;
  const int srow = t >> 2, scol = (t & 3) * 16;
  const u16* kbase = qkv + (size_t)b*512*1536 + 512 + h*64;
  const u16* vbase = vT + (size_t)bh*64*512;

  // Q fragment (needed immediately for Pr build)
  short8 af0, af1;
  {
    const u16* qp = qkv + (token0 + w*16 + lr)*1536 + h*64 + quad*8;
    af0 = *(const short8*)(qp);
    af1 = *(const short8*)(qp + 32);
  }

  // prefetch kt=0 K/V into regs; latency hides under Pr build below
  uint4 kr0, kr1, vr0, vr1;
  {
    const u16* kp = kbase + (size_t)srow*1536 + scol;
    kr0 = *(const uint4*)kp; kr1 = *(const uint4*)(kp + 8);
    const u16* vp = vbase + (size_t)srow*512 + scol;
    vr0 = *(const uint4*)vp; vr1 = *(const uint4*)(vp + 8);
  }

  // Pr[q][j] = (Q[q] . relB[j]) * log2(e); rows w*16+quad*4+r are wave-private
  // (read side uses rows w*16+lr -> same 16-row slab, same wave -> in-order
  //  DS pipe makes RAW safe without barriers).
  #pragma unroll 4
  for (int nt = 0; nt < 17; ++nt) {
    const u16* rp = relB + (nt*16 + lr)*64 + quad*8;
    short8 rb0 = *(const short8*)(rp);
    short8 rb1 = *(const short8*)(rp + 32);
    floatx4 c = {0.f,0.f,0.f,0.f};
    c = __builtin_amdgcn_mfma_f32_16x16x32_bf16(af0, rb0, c, 0, 0, 0);
    c = __builtin_amdgcn_mfma_f32_16x16x32_bf16(af1, rb1, c, 0, 0, 0);
    #pragma unroll
    for (int r = 0; r < 4; ++r)
      Pr[(w*16 + quad*4 + r)*274 + nt*16 + lr] = f2b(c[r] * 1.44269504f);
  }

  floatx4 oacc[4];
  float lacc = 0.f;
  #pragma unroll
  for (int n = 0; n < 4; ++n) { floatx4 zz = {0.f,0.f,0.f,0.f}; oacc[n] = zz; }

  const int qglob = qt*64 + w*16 + lr;          // this lane's q (global)
  const int prbase = (w*16 + lr)*274 + 128;     // Pr row base + clamp offset

  // boundary biases for fully-clamped tiles (per-lane constants)
  const float prLo = b2f(Pr[prbase - 128]);     // dd = -128
  const float prHi = b2f(Pr[prbase + 128]);     // dd = +128

  for (int kt = 0; kt < 8; ++kt) {
    __syncthreads();  // A: prev iter's Ks/Vs readers done before overwrite
    *(uint4*)&Ks[srow*72 + scol]     = kr0;
    *(uint4*)&Ks[srow*72 + scol + 8] = kr1;
    *(uint4*)&Vs[srow*72 + scol]     = vr0;
    *(uint4*)&Vs[srow*72 + scol + 8] = vr1;
    __syncthreads();  // B: staging visible

    // T14: issue NEXT tile's global loads now; consumed at next iter's write.
    if (kt < 7) {
      const u16* kp = kbase + (size_t)((kt+1)*64 + srow)*1536 + scol;
      kr0 = *(const uint4*)kp; kr1 = *(const uint4*)(kp + 8);
      const u16* vp = vbase + (size_t)srow*512 + (kt+1)*64 + scol;
      vr0 = *(const uint4*)vp; vr1 = *(const uint4*)(vp + 8);
    }

    // S^T = K . Q^T  (lane: col=lr -> q fixed, row=quad*4+r -> k-local)
    floatx4 s4[4];
    __builtin_amdgcn_s_setprio(1);
    #pragma unroll
    for (int nt = 0; nt < 4; ++nt) {
      short8 kb0 = *(const short8*)&Ks[(nt*16 + lr)*72 + quad*8];
      short8 kb1 = *(const short8*)&Ks[(nt*16 + lr)*72 + 32 + quad*8];
      floatx4 c = {0.f,0.f,0.f,0.f};
      c = __builtin_amdgcn_mfma_f32_16x16x32_bf16(kb0, af0, c, 0, 0, 0);
      c = __builtin_amdgcn_mfma_f32_16x16x32_bf16(kb1, af1, c, 0, 0, 0);
      s4[nt] = c;
    }
    __builtin_amdgcn_s_setprio(0);

    // P = exp2(S*0.125*log2e + bias), packed to bf16 pairs.
    // Wave-uniform tile classification vs the clamp band:
    const int tmin = kt*64 - (qt*64 + w*16 + 15);   // min dd over wave tile
    const int tmax = tmin + 78;                     // max dd
    u32 wq[4][2];
    const int kq = kt*64 + quad*4 - qglob;
    if (tmin >= 128 || tmax <= -128) {
      // fully clamped: bias constant per lane
      const float pc = (tmin >= 128) ? prHi : prLo;
      #pragma unroll
      for (int nt = 0; nt < 4; ++nt) {
        float p[4];
        #pragma unroll
        for (int r = 0; r < 4; ++r)
          p[r] = exp2f(fmaf(s4[nt][r], 0.18033688f, pc));
        lacc += (p[0] + p[1]) + (p[2] + p[3]);
        wq[nt][0] = cvtpk(p[0], p[1]);
        wq[nt][1] = cvtpk(p[2], p[3]);
      }
    } else if (tmin >= -128 && tmax <= 128) {
      // interior: no clamp needed
      #pragma unroll
      for (int nt = 0; nt < 4; ++nt) {
        const int dbase = kq + nt*16;
        float p[4];
        #pragma unroll
        for (int r = 0; r < 4; ++r)
          p[r] = exp2f(fmaf(s4[nt][r], 0.18033688f, b2f(Pr[prbase + dbase + r])));
        lacc += (p[0] + p[1]) + (p[2] + p[3]);
        wq[nt][0] = cvtpk(p[0], p[1]);
        wq[nt][1] = cvtpk(p[2], p[3]);
      }
    } else {
      // partial: clamped gather (original path)
      #pragma unroll
      for (int nt = 0; nt < 4; ++nt) {
        const int dbase = kq + nt*16;
        float p[4];
        #pragma unroll
        for (int r = 0; r < 4; ++r) {
          int dd = dbase + r;
          dd = dd < -128 ? -128 : (dd > 128 ? 128 : dd);
          p[r] = exp2f(fmaf(s4[nt][r], 0.18033688f, b2f(Pr[prbase + dd])));
        }
        lacc += (p[0] + p[1]) + (p[2] + p[3]);
        wq[nt][0] = cvtpk(p[0], p[1]);
        wq[nt][1] = cvtpk(p[2], p[3]);
      }
    }

    // PV B-fragments assembled in registers (sigma absorbed into vb reads)
    intx4 pw0; pw0.x = (int)wq[0][0]; pw0.y = (int)wq[0][1];
               pw0.z = (int)wq[1][0]; pw0.w = (int)wq[1][1];
    intx4 pw1; pw1.x = (int)wq[2][0]; pw1.y = (int)wq[2][1];
               pw1.z = (int)wq[3][0]; pw1.w = (int)wq[3][1];
    const short8 pf0 = __builtin_bit_cast(short8, pw0);
    const short8 pf1 = __builtin_bit_cast(short8, pw1);

    // O += V x P : A-frag vb[row=d][kk] = V^T[d][sigma(kk)];
    // sigma(kk = quad*8+j) = (j>>2)*16 + quad*4 + (j&3)  (+32 for pf1 half)
    __builtin_amdgcn_s_setprio(1);
    #pragma unroll
    for (int nd = 0; nd < 4; ++nd) {
      const int vrow = (nd*16 + lr)*72;
      uint2 a0 = *(const uint2*)&Vs[vrow + quad*4];
      uint2 a1 = *(const uint2*)&Vs[vrow + 16 + quad*4];
      uint2 a2 = *(const uint2*)&Vs[vrow + 32 + quad*4];
      uint2 a3 = *(const uint2*)&Vs[vrow + 48 + quad*4];
      intx4 v0; v0.x = (int)a0.x; v0.y = (int)a0.y; v0.z = (int)a1.x; v0.w = (int)a1.y;
      intx4 v1; v1.x = (int)a2.x; v1.y = (int)a2.y; v1.z = (int)a3.x; v1.w = (int)a3.y;
      const short8 vb0 = __builtin_bit_cast(short8, v0);
      const short8 vb1 = __builtin_bit_cast(short8, v1);
      oacc[nd] = __builtin_amdgcn_mfma_f32_16x16x32_bf16(vb0, pf0, oacc[nd], 0, 0, 0);
      oacc[nd] = __builtin_amdgcn_mfma_f32_16x16x32_bf16(vb1, pf1, oacc[nd], 0, 0, 0);
    }
    __builtin_amdgcn_s_setprio(0);
  }

  // cross-quad denominator reduce (q = lr is shared by the 4 quads)
  lacc += __shfl_xor(lacc, 16);
  lacc += __shfl_xor(lacc, 32);

  // epilogue: q = lr (fixed per lane); lane writes d = nd*16 + quad*4 + v
  {
    const float inv = 1.f / lacc;
    u16* cp = ctx + (token0 + w*16 + lr)*512 + h*64;
    #pragma unroll
    for (int nd = 0; nd < 4; ++nd) {
      const int d = nd*16 + quad*4;
      uint2 o;
      o.x = pack2(oacc[nd][0]*inv, oacc[nd][1]*inv);
      o.y = pack2(oacc[nd][2]*inv, oacc[nd][3]*inv);
      *(uint2*)(cp + d) = o;
    }
  }
}

// ---------------------------------------------------------------------------
// LayerNorm over D=512, R11: ONE WAVE PER ROW — 64 lanes x 8 elems, uint4
// bf16 loads (16B/lane), pure shfl_xor reductions. ZERO barriers, ZERO LDS
// (was 2 waves/row + LDS round-trip + 4 __syncthreads + 4B loads).
// 4 rows per 256-thread block -> grid 2048.
// ---------------------------------------------------------------------------
__global__ __launch_bounds__(256) void ln_kernel(
    const u16* __restrict__ resB, const float* __restrict__ add0,
    const float* __restrict__ add1,
    const float* __restrict__ g, const float* __restrict__ be,
    u16* __restrict__ hb)
{
  const int wv = threadIdx.x >> 6, ln = threadIdx.x & 63;
  const int row = blockIdx.x * 4 + wv;
  const size_t base = (size_t)row * 512;
  const int off = ln * 8;

  const uint4 rv = *(const uint4*)(resB + base + off);
  float x[8];
  x[0] = lo16(rv.x); x[1] = hi16(rv.x);
  x[2] = lo16(rv.y); x[3] = hi16(rv.y);
  x[4] = lo16(rv.z); x[5] = hi16(rv.z);
  x[6] = lo16(rv.w); x[7] = hi16(rv.w);
  if (add0) {
    const float4 a0 = *(const float4*)(add0 + base + off);
    const float4 a1 = *(const float4*)(add0 + base + off + 4);
    x[0] += a0.x; x[1] += a0.y; x[2] += a0.z; x[3] += a0.w;
    x[4] += a1.x; x[5] += a1.y; x[6] += a1.z; x[7] += a1.w;
  }
  if (add1) {
    const float4 a0 = *(const float4*)(add1 + base + off);
    const float4 a1 = *(const float4*)(add1 + base + off + 4);
    x[0] += a0.x; x[1] += a0.y; x[2] += a0.z; x[3] += a0.w;
    x[4] += a1.x; x[5] += a1.y; x[6] += a1.z; x[7] += a1.w;
  }

  float s = ((x[0]+x[1]) + (x[2]+x[3])) + ((x[4]+x[5]) + (x[6]+x[7]));
  #pragma unroll
  for (int o = 1; o < 64; o <<= 1) s += __shfl_xor(s, o);
  const float mean = s * (1.f/512.f);

  float vs = 0.f;
  #pragma unroll
  for (int i = 0; i < 8; ++i) { const float d = x[i] - mean; vs = fmaf(d, d, vs); }
  #pragma unroll
  for (int o = 1; o < 64; o <<= 1) vs += __shfl_xor(vs, o);
  const float inv = 1.f / sqrtf(vs * (1.f/512.f) + 1e-5f);

  const float4 g0 = *(const float4*)(g + off);
  const float4 g1 = *(const float4*)(g + off + 4);
  const float4 b0 = *(const float4*)(be + off);
  const float4 b1 = *(const float4*)(be + off + 4);
  const float y0 = (x[0]-mean)*inv*g0.x + b0.x;
  const float y1 = (x[1]-mean)*inv*g0.y + b0.y;
  const float y2 = (x[2]-mean)*inv*g0.z + b0.z;
  const float y3 = (x[3]-mean)*inv*g0.w + b0.w;
  const float y4 = (x[4]-mean)*inv*g1.x + b1.x;
  const float y5 = (x[5]-mean)*inv*g1.y + b1.y;
  const float y6 = (x[6]-mean)*inv*g1.z + b1.z;
  const float y7 = (x[7]-mean)*inv*g1.w + b1.w;
  uint4 o;
  o.x = pack2(y0, y1); o.y = pack2(y2, y3);
  o.z = pack2(y4, y5); o.w = pack2(y6, y7);
  *(uint4*)(hb + base + off) = o;
}

// ---------------------------------------------------------------------------
// out[row] = hd1[row][:] . p2_w + p2_b   (256-dot, one wave per row), f32 out
// ---------------------------------------------------------------------------
__global__ __launch_bounds__(256) void head2_kernel(
    const u16* __restrict__ hd1, const float* __restrict__ p2w,
    const float* __restrict__ p2b, float* __restrict__ out)
{
  const int wv = threadIdx.x >> 6, ln = threadIdx.x & 63;
  const int row = blockIdx.x * 4 + wv;
  const u16* hp = hd1 + (size_t)row * 256 + ln*4;
  const u32 h0 = *(const u32*)hp, h1 = *(const u32*)(hp + 2);
  const float4 w = *(const float4*)(p2w + ln*4);
  float acc = lo16(h0)*w.x + hi16(h0)*w.y + lo16(h1)*w.z + hi16(h1)*w.w;
  #pragma unroll
  for (int off = 1; off < 64; off <<= 1) acc += __shfl_xor(acc, off);
  if (ln == 0) out[row] = acc + p2b[0];
}

// ---------------------------------------------------------------------------
extern "C" void kernel_launch(void* const* d_in, const int* in_sizes, int n_in,
                              void* d_out, int out_size, void* d_ws, size_t ws_size,
                              hipStream_t stream) {
  (void)in_sizes; (void)n_in; (void)out_size; (void)ws_size;
  const float* X    = (const float*)d_in[0];
  const float* INW  = (const float*)d_in[1];
  const float* INB  = (const float*)d_in[2];
  const float* WQ   = (const float*)d_in[3];
  const float* WK   = (const float*)d_in[4];
  const float* WV   = (const float*)d_in[5];
  const float* WO   = (const float*)d_in[6];
  const float* BO   = (const float*)d_in[7];
  const float* REL  = (const float*)d_in[8];
  const float* W1   = (const float*)d_in[9];
  const float* B1   = (const float*)d_in[10];
  const float* W2   = (const float*)d_in[11];
  const float* B2   = (const float*)d_in[12];
  const float* LN1G = (const float*)d_in[13];
  const float* LN1B = (const float*)d_in[14];
  const float* LN2G = (const float*)d_in[15];
  const float* LN2B = (const float*)d_in[16];
  const float* ONG  = (const float*)d_in[17];
  const float* ONB  = (const float*)d_in[18];
  const float* P1W  = (const float*)d_in[19];
  const float* P1B  = (const float*)d_in[20];
  const float* P2W  = (const float*)d_in[21];
  const float* P2B  = (const float*)d_in[22];
  float* out = (float*)d_out;

  char* ws = (char*)d_ws;
  u16*   wT    = (u16*)(ws + OFF_WT);
  u16*   hB    = (u16*)(ws + OFF_HB);
  u16*   qkv   = (u16*)(ws + OFF_QKV);
  u16*   ctx   = (u16*)(ws + OFF_CTX);
  float* gout0 = (float*)(ws + OFF_GOUT);
  float* gout1 = (float*)(ws + OFF_QKV);   // alias: dead during Wo/FFN2
  u16*   ff    = (u16*)(ws + OFF_FF);
  u16*   hd1   = (u16*)(ws + OFF_HD1);
  u16*   vTb   = (u16*)(ws + OFF_VT);
  u16*   relBa = (u16*)(ws + OFF_RELB);

  transpose_all<<<4640, 256, 0, stream>>>(WQ, WK, WV, WO, W1, W2, P1W, wT);
  cvt_rel_all<<<386, 256, 0, stream>>>(REL, relBa);
  input_proj<<<NTOK, 128, 0, stream>>>(X, INW, INB, hB);

  for (int l = 0; l < NLAYER; ++l) {
    const u16* wTl = wT + (size_t)l * LSTRIDE;
    // QKV fused: [8192,512] @ [512,1536]; Q,K -> qkv bf16, V -> vT transposed
    gemm_bt<<<dim3(768,1), 256, 0, stream>>>(hB, wTl, nullptr, nullptr, nullptr, qkv, vTb,
                                             8192, 1536, 512, 512, 4);
    attn_mfma<<<1024, 256, 0, stream>>>(qkv, vTb, relBa + l*17408, ctx);
    // Wo + bo, split-K=2 -> f32 partials
    gemm_bt<<<dim3(256,2), 256, 0, stream>>>(ctx, wTl + 786432, BO + l*512,
                                             gout0, gout1, nullptr, nullptr,
                                             8192, 512, 512, 256, 1);
    ln_kernel<<<2048, 256, 0, stream>>>(hB, gout0, gout1, LN1G + l*512, LN1B + l*512, hB);
    // FFN1: relu(h @ w1 + b1) -> bf16  (overwrites vT scratch - dead)
    gemm_bt<<<dim3(1024,1), 256, 0, stream>>>(hB, wTl + 1048576, B1 + l*2048,
                                              nullptr, nullptr, ff, nullptr,
                                              8192, 2048, 512, 512, 3);
    // FFN2: ff @ w2 + b2, split-K=2 -> f32 partials
    gemm_bt<<<dim3(256,2), 256, 0, stream>>>(ff, wTl + 2097152, B2 + l*512,
                                             gout0, gout1, nullptr, nullptr,
                                             8192, 512, 2048, 1024, 1);
    ln_kernel<<<2048, 256, 0, stream>>>(hB, gout0, gout1, LN2G + l*512, LN2B + l*512, hB);
  }
  ln_kernel<<<2048, 256, 0, stream>>>(hB, nullptr, nullptr, ONG, ONB, hB);
  // head: relu(h @ p1_w + p1_b) -> bf16 [8192][256]
  gemm_bt<<<dim3(128,1), 256, 0, stream>>>(hB, wT + P1T_OFF, P1B,
                                           nullptr, nullptr, hd1, nullptr,
                                           8192, 256, 512, 512, 3);
  head2_kernel<<<2048, 256, 0, stream>>>(hd1, P2W, P2B, out);
}

// Round 12
// 1074.716 us; speedup vs baseline: 1.2648x; 1.0041x over previous
//
#include <hip/hip_runtime.h>

typedef unsigned short u16;
typedef unsigned int   u32;
typedef short   short8  __attribute__((ext_vector_type(8)));
typedef float   floatx4 __attribute__((ext_vector_type(4)));
typedef int     intx4   __attribute__((ext_vector_type(4)));

#define NTOK 8192
#define SEQ  512
#define NLAYER 6

// ---- workspace layout (bytes) ----
#define OFF_WT   ((size_t)0)          // transposed weights (bf16), 19,005,440 u16
#define OFF_HB   ((size_t)38010880)   // h bf16   [8192][512] (residual stream)
#define OFF_QKV  ((size_t)46399488)   // qkv bf16 [8192][1536] (25.2 MB)
#define OFF_CTX  ((size_t)71565312)   // ctx bf16 [8192][512]
#define OFF_GOUT ((size_t)79953920)   // gout0 partial, now bf16 [8192][512]
#define OFF_FF   ((size_t)96731136)   // ff bf16  [8192][2048]  (33.5 MB)
#define OFF_HD1  ((size_t)130285568)  // head1 bf16 [8192][256] (4.2 MB)
// aliases:
//   gout1 (split-K partial, bf16 [8192][512]) -> qkv region (dead during Wo/FFN2)
//   vT bf16 [128 bh][64][512] (8.4 MB) -> ff region (dead during attn)
//   relB_all bf16 [6][272][64] (209 KB) -> hd1 region (hd1 written only at end)
#define OFF_VT   OFF_FF
#define OFF_RELB OFF_HD1

#define LSTRIDE 3145728   // wT elems per layer: [QT;KT;VT](1536x512), WoT, w1T(2048x512), w2T(512x2048)
#define P1T_OFF 18874368  // p1T [256][512]

__device__ __forceinline__ float b2f(u16 v) { return __uint_as_float(((u32)v) << 16); }
__device__ __forceinline__ float lo16(u32 v) { return __uint_as_float(v << 16); }
__device__ __forceinline__ float hi16(u32 v) { return __uint_as_float(v & 0xffff0000u); }
__device__ __forceinline__ u16 f2b(float f) {
  u32 x = __float_as_uint(f);
  return (u16)((x + 0x7fffu + ((x >> 16) & 1u)) >> 16);
}
__device__ __forceinline__ u32 pack2(float a, float b) {
  return (u32)f2b(a) | ((u32)f2b(b) << 16);
}
__device__ __forceinline__ u32 cvtpk(float a, float b) {
  u32 r;
  asm("v_cvt_pk_bf16_f32 %0, %1, %2" : "=v"(r) : "v"(a), "v"(b));
  return r;
}

typedef __attribute__((address_space(1))) void* gas_t;
typedef __attribute__((address_space(3))) void* las_t;

// ---------------------------------------------------------------------------
// Transpose all f32 weight matrices into wT, in MFMA-FRAGMENT-PACKED layout:
// element (n,k) of logical Bt[N][K] lives at
//   (((n>>7)*(K>>5) + (k>>5))*8 + ((n>>4)&7))*512
//   + (((k>>3)&3)*16 + (n&15))*8 + (k&7)
// so fragment (nb,kc,j) is 512 contiguous u16 and lane l's short8 is at l*8:
// gemm_bt loads B operands straight from global as coalesced 1 KB reads.
// ---------------------------------------------------------------------------
__global__ __launch_bounds__(256) void transpose_all(
    const float* __restrict__ Wq, const float* __restrict__ Wk,
    const float* __restrict__ Wv, const float* __restrict__ Wo,
    const float* __restrict__ w1, const float* __restrict__ w2,
    const float* __restrict__ p1, u16* __restrict__ wT)
{
  __shared__ u16 tile[64][65];
  const int tb = blockIdx.x;
  const float* src; u16* dst; int R, C, tidx;
  if (tb < 4608) {
    const int l = tb / 768, r = tb % 768;
    const size_t lofs = (size_t)l * LSTRIDE;
    if (r < 256) {
      const int m = r >> 6; tidx = r & 63; R = 512; C = 512;
      const float* bases[4] = {Wq, Wk, Wv, Wo};
      src = bases[m] + (size_t)l * 262144;
      dst = wT + lofs + (size_t)m * 262144;
    } else if (r < 512) {
      tidx = r - 256; R = 512; C = 2048;
      src = w1 + (size_t)l * 1048576; dst = wT + lofs + 1048576;
    } else {
      tidx = r - 512; R = 2048; C = 512;
      src = w2 + (size_t)l * 1048576; dst = wT + lofs + 2097152;
    }
  } else {
    tidx = tb - 4608; R = 512; C = 256;
    src = p1; dst = wT + P1T_OFF;
  }
  // src is W[R=K][C=N]; logical dst Bt[N][K] but stored fragment-packed.
  const int tcn = C >> 6;
  const int tr = tidx / tcn, tc = tidx % tcn;
  const int th = threadIdx.x;
  {
    const int lr = th >> 2, cg = (th & 3) * 16;
    const float* sp = src + (size_t)(tr*64 + lr) * C + tc*64 + cg;
    float4 f0 = *(const float4*)(sp);
    float4 f1 = *(const float4*)(sp + 4);
    float4 f2 = *(const float4*)(sp + 8);
    float4 f3 = *(const float4*)(sp + 12);
    u16* tp = &tile[lr][cg];
    tp[0]=f2b(f0.x); tp[1]=f2b(f0.y); tp[2]=f2b(f0.z); tp[3]=f2b(f0.w);
    tp[4]=f2b(f1.x); tp[5]=f2b(f1.y); tp[6]=f2b(f1.z); tp[7]=f2b(f1.w);
    tp[8]=f2b(f2.x); tp[9]=f2b(f2.y); tp[10]=f2b(f2.z); tp[11]=f2b(f2.w);
    tp[12]=f2b(f3.x); tp[13]=f2b(f3.y); tp[14]=f2b(f3.z); tp[15]=f2b(f3.w);
  }
  __syncthreads();
  {
    const int oc = th >> 2, rg = (th & 3) * 16;
    u32 wds[8];
    #pragma unroll
    for (int i = 0; i < 8; ++i)
      wds[i] = (u32)tile[rg + 2*i][oc] | ((u32)tile[rg + 2*i + 1][oc] << 16);
    const int n  = tc*64 + oc;            // N-dim index
    const int k0 = tr*64 + rg;            // K-dim index, 16-aligned
    const int nb = n >> 7, j = (n >> 4) & 7, lr = n & 15;
    const int kc = k0 >> 5, lq = (k0 >> 3) & 3;   // lq in {0,2}
    const int KC = R >> 5;
    u16* base = dst + (((((size_t)nb*KC + kc) << 3) + j) << 9);
    uint4 o0; o0.x=wds[0]; o0.y=wds[1]; o0.z=wds[2]; o0.w=wds[3];
    uint4 o1; o1.x=wds[4]; o1.y=wds[5]; o1.z=wds[6]; o1.w=wds[7];
    *(uint4*)(base + (lq*16 + lr)*8)       = o0;  // k0..k0+7
    *(uint4*)(base + ((lq+1)*16 + lr)*8)   = o1;  // k0+8..k0+15
  }
}

// ---------------------------------------------------------------------------
// h = x @ in_w + in_b + sinusoidal_pe   (K=50) -> bf16
// Each thread owns 4 consecutive d: 50 float4 loads, 2 __sincosf.
// ---------------------------------------------------------------------------
__global__ __launch_bounds__(128) void input_proj(
    const float* __restrict__ x, const float* __restrict__ w, const float* __restrict__ ib,
    u16* __restrict__ hb)
{
  const int row = blockIdx.x, t = threadIdx.x;
  const int s = row & (SEQ - 1);
  __shared__ float xs[50];
  if (t < 50) xs[t] = x[row*50 + t];
  __syncthreads();
  const int d0 = t * 4;                    // even; covers 512 with 128 threads
  float4 acc = *(const float4*)(ib + d0);
  #pragma unroll
  for (int i = 0; i < 50; ++i) {
    const float4 wv = *(const float4*)(w + i*512 + d0);
    const float xv = xs[i];
    acc.x = fmaf(xv, wv.x, acc.x);
    acc.y = fmaf(xv, wv.y, acc.y);
    acc.z = fmaf(xv, wv.z, acc.z);
    acc.w = fmaf(xv, wv.w, acc.w);
  }
  const float cexp = -0.017988946f;        // -ln(10000)/512
  const float dv0 = __expf((float)d0 * cexp);
  const float dv1 = __expf((float)(d0 + 2) * cexp);
  float s0, c0, s1, c1;
  __sincosf((float)s * dv0, &s0, &c0);
  __sincosf((float)s * dv1, &s1, &c1);
  acc.x += s0; acc.y += c0; acc.z += s1; acc.w += c1;
  u32* hp = (u32*)(hb + (size_t)row*512 + d0);
  hp[0] = pack2(acc.x, acc.y);
  hp[1] = pack2(acc.z, acc.w);
}

// ---------------------------------------------------------------------------
// C[M][N] = A[M][K] @ Bt[N][K]^T over k in [z*kLen, (z+1)*kLen)
// R6: B consumed directly from global in fragment-packed layout; only A is
// LDS-staged (double-buffered 2x16 KB).
// R12: split-K partials are written as BF16 (outP0/outP1, uint2 stores) —
// halves partial write traffic + LN re-read traffic (the partials were the
// only remaining f32 tensors; one extra bf16 rounding before a LayerNorm).
// ---------------------------------------------------------------------------
__global__ __launch_bounds__(256, 4) void gemm_bt(
    const u16* __restrict__ A, const u16* __restrict__ Bt,
    const float* __restrict__ bias,
    u16* __restrict__ outP0, u16* __restrict__ outP1, u16* __restrict__ outB,
    u16* __restrict__ vTout,
    const int M, const int N, const int K, const int kLen, const int flags)
{
  __shared__ __align__(16) u16 As[2][8192];   // [buf][hh*4096 + row*32 + k32]
  const int id = blockIdx.x;
  const int xcd = id & 7, rest = id >> 3;
  const int bm = (rest & 7) * 8 + xcd;
  const int bn = rest >> 3;
  const int z = blockIdx.y;
  const int kOff = z * kLen;
  const int m0 = bm << 7, n0 = bn << 7;
  const int tid = threadIdx.x;
  const int wave = tid >> 6, lane = tid & 63;
  const int wr = (wave >> 1) << 6, wc = (wave & 1) << 6;
  const int lrow = lane & 15, lquad = lane >> 4;

  floatx4 acc[4][4];
  #pragma unroll
  for (int i = 0; i < 4; ++i)
    #pragma unroll
    for (int j = 0; j < 4; ++j) { floatx4 zz = {0.f,0.f,0.f,0.f}; acc[i][j] = zz; }

  const u16* a0p = A + (size_t)m0 * K + kOff;
  const int c0 = tid, c1 = 256 + tid;
  const int ar0 = c0 >> 2, as0 = (c0 & 3) * 8;
  const int ar1 = c1 >> 2, as1 = (c1 & 3) * 8;
  const int KC = K >> 5;
  // base of this wave's B-fragment stream: (bn, kc=kOff/32, jglob=(wave&1)*4)
  const u16* bW = Bt + ((((size_t)bn*KC + (kOff >> 5)) * 8 + (wave & 1) * 4) << 9) + lane*8;

#define STAGE_A(buf, k0) do {                                                                  \
    __builtin_amdgcn_global_load_lds((gas_t)(a0p + (size_t)ar0*K + (k0) + as0),                \
                                     (las_t)(&As[buf][c0*8]), 16, 0, 0);                       \
    __builtin_amdgcn_global_load_lds((gas_t)(a0p + (size_t)ar1*K + (k0) + as1),                \
                                     (las_t)(&As[buf][c1*8]), 16, 0, 0);                       \
    __builtin_amdgcn_global_load_lds((gas_t)(a0p + (size_t)ar0*K + (k0) + 32 + as0),           \
                                     (las_t)(&As[buf][4096 + c0*8]), 16, 0, 0);                \
    __builtin_amdgcn_global_load_lds((gas_t)(a0p + (size_t)ar1*K + (k0) + 32 + as1),           \
                                     (las_t)(&As[buf][4096 + c1*8]), 16, 0, 0);                \
  } while (0)

  const int nst = kLen >> 6;
  STAGE_A(0, 0);
  __syncthreads();

  int cur = 0;
  for (int t = 0; t < nst; ++t) {
    // B fragments for this chunk, straight from global (packed layout).
    const u16* bc = bW + (size_t)(2*t) * 4096;
    short8 b0[4], b1[4];
    #pragma unroll
    for (int j = 0; j < 4; ++j) b0[j] = *(const short8*)(bc + j*512);
    if (t + 1 < nst) STAGE_A(cur ^ 1, (t + 1) * 64);
    #pragma unroll
    for (int j = 0; j < 4; ++j) b1[j] = *(const short8*)(bc + 4096 + j*512);
    // hh = 0
    {
      short8 af[4];
      #pragma unroll
      for (int i = 0; i < 4; ++i) af[i] = *(const short8*)&As[cur][(wr + i*16 + lrow)*32 + lquad*8];
      #pragma unroll
      for (int i = 0; i < 4; ++i)
        #pragma unroll
        for (int j = 0; j < 4; ++j)
          acc[i][j] = __builtin_amdgcn_mfma_f32_16x16x32_bf16(b0[j], af[i], acc[i][j], 0, 0, 0);
    }
    // hh = 1
    {
      short8 af[4];
      #pragma unroll
      for (int i = 0; i < 4; ++i) af[i] = *(const short8*)&As[cur][4096 + (wr + i*16 + lrow)*32 + lquad*8];
      #pragma unroll
      for (int i = 0; i < 4; ++i)
        #pragma unroll
        for (int j = 0; j < 4; ++j)
          acc[i][j] = __builtin_amdgcn_mfma_f32_16x16x32_bf16(b1[j], af[i], acc[i][j], 0, 0, 0);
    }
    if (t + 1 < nst) { __syncthreads(); cur ^= 1; }
  }
#undef STAGE_A

  // Swapped layout: lane owns row = m0+wr+i*16+lrow (fixed),
  //                 cols = n0+wc+j*16+lquad*4 + v (v=0..3 consecutive)
  if ((flags & 4) && n0 >= 1024) {
    // V block of QKV: write into vT[(b*8+h)*64+d][s] (bf16), scalar stores
    #pragma unroll
    for (int i = 0; i < 4; ++i) {
      const int row = m0 + wr + i*16 + lrow;
      const int bb = row >> 9, s = row & 511;
      #pragma unroll
      for (int j = 0; j < 4; ++j) {
        const int cm0 = (n0 - 1024) + wc + j*16 + lquad*4;
        #pragma unroll
        for (int v = 0; v < 4; ++v) {
          const int cm = cm0 + v;
          const int hh = cm >> 6, d = cm & 63;
          vTout[((size_t)(bb*8 + hh)*64 + d)*512 + s] = f2b(acc[i][j][v]);
        }
      }
    }
    return;
  }

  u16* outT = outB ? outB : ((z == 0) ? outP0 : outP1);
  const bool hasb = ((flags & 1) != 0) && (z == 0);
  const bool dorelu = (flags & 2) != 0;
  #pragma unroll
  for (int i = 0; i < 4; ++i) {
    const int row = m0 + wr + i*16 + lrow;
    #pragma unroll
    for (int j = 0; j < 4; ++j) {
      const int colbase = n0 + wc + j*16 + lquad*4;
      float4 bv4 = make_float4(0.f, 0.f, 0.f, 0.f);
      if (hasb) bv4 = *(const float4*)(bias + colbase);
      float v0 = acc[i][j][0] + bv4.x;
      float v1 = acc[i][j][1] + bv4.y;
      float v2 = acc[i][j][2] + bv4.z;
      float v3 = acc[i][j][3] + bv4.w;
      if (dorelu) {
        v0 = fmaxf(v0, 0.f); v1 = fmaxf(v1, 0.f);
        v2 = fmaxf(v2, 0.f); v3 = fmaxf(v3, 0.f);
      }
      const size_t off = (size_t)row * N + colbase;
      uint2 o; o.x = pack2(v0, v1); o.y = pack2(v2, v3);
      *(uint2*)(outT + off) = o;
    }
  }
}

// ---------------------------------------------------------------------------
// All layers' rel_emb f32 [6][257][64] -> bf16 relB_all [6][272][64]
// ---------------------------------------------------------------------------
__global__ __launch_bounds__(256) void cvt_rel_all(
    const float* __restrict__ rel, u16* __restrict__ relB)
{
  const int i = blockIdx.x*256 + threadIdx.x;
  if (i < 6*257*64) {
    const int l = i / 16448, rem = i % 16448;
    relB[l*17408 + rem] = f2b(rel[i]);
  }
}

// ---------------------------------------------------------------------------
// MFMA flash attention, S^T / register-P version (EXACT R7 structure —
// measured 40.6 us, the empirical optimum; R8/R9 occupancy pushes both
// regressed: attn is barrier/serial-chain bound, not occupancy bound).
// Band-specialized rel-bias (R7), register-P PV (R3), T14 K/V reg-prefetch,
// T5 setprio. LDS: Ks 9216 + Vs 9216 + Pr 64*274*2=35072 -> 3 blocks/CU.
// ---------------------------------------------------------------------------
__global__ __launch_bounds__(256, 3) void attn_mfma(
    const u16* __restrict__ qkv, const u16* __restrict__ vT,
    const u16* __restrict__ relB, u16* __restrict__ ctx)
{
  const int id = blockIdx.x;
  const int xcd = id & 7, g = (id >> 3) & 15, qt = id >> 7;
  const int bh = xcd*16 + g;
  const int b = bh >> 3, h = bh & 7;
  const int t = threadIdx.x, w = t >> 6, lane = t & 63;
  const int lr = lane & 15, quad = lane >> 4;

  __shared__ __align__(16) u16 Ks[64*72];
  __shared__ __align__(16) u16 Vs[64*72];
  __shared__ __align__(16) u16 Pr[64*274];  // rel-bias table (pre-scaled log2e)

  const size_t token0 = (size_t)b*512 + qt*64;
  const int srow = t >> 2, scol = (t & 3) * 16;
  const u16* kbase = qkv + (size_t)b*512*1536 + 512 + h*64;
  const u16* vbase = vT + (size_t)bh*64*512;

  // Q fragment (needed immediately for Pr build)
  short8 af0, af1;
  {
    const u16* qp = qkv + (token0 + w*16 + lr)*1536 + h*64 + quad*8;
    af0 = *(const short8*)(qp);
    af1 = *(const short8*)(qp + 32);
  }

  // prefetch kt=0 K/V into regs; latency hides under Pr build below
  uint4 kr0, kr1, vr0, vr1;
  {
    const u16* kp = kbase + (size_t)srow*1536 + scol;
    kr0 = *(const uint4*)kp; kr1 = *(const uint4*)(kp + 8);
    const u16* vp = vbase + (size_t)srow*512 + scol;
    vr0 = *(const uint4*)vp; vr1 = *(const uint4*)(vp + 8);
  }

  // Pr[q][j] = (Q[q] . relB[j]) * log2(e); rows w*16+quad*4+r are wave-private
  // (read side uses rows w*16+lr -> same 16-row slab, same wave -> in-order
  //  DS pipe makes RAW safe without barriers).
  #pragma unroll 4
  for (int nt = 0; nt < 17; ++nt) {
    const u16* rp = relB + (nt*16 + lr)*64 + quad*8;
    short8 rb0 = *(const short8*)(rp);
    short8 rb1 = *(const short8*)(rp + 32);
    floatx4 c = {0.f,0.f,0.f,0.f};
    c = __builtin_amdgcn_mfma_f32_16x16x32_bf16(af0, rb0, c, 0, 0, 0);
    c = __builtin_amdgcn_mfma_f32_16x16x32_bf16(af1, rb1, c, 0, 0, 0);
    #pragma unroll
    for (int r = 0; r < 4; ++r)
      Pr[(w*16 + quad*4 + r)*274 + nt*16 + lr] = f2b(c[r] * 1.44269504f);
  }

  floatx4 oacc[4];
  float lacc = 0.f;
  #pragma unroll
  for (int n = 0; n < 4; ++n) { floatx4 zz = {0.f,0.f,0.f,0.f}; oacc[n] = zz; }

  const int qglob = qt*64 + w*16 + lr;          // this lane's q (global)
  const int prbase = (w*16 + lr)*274 + 128;     // Pr row base + clamp offset

  // boundary biases for fully-clamped tiles (per-lane constants)
  const float prLo = b2f(Pr[prbase - 128]);     // dd = -128
  const float prHi = b2f(Pr[prbase + 128]);     // dd = +128

  for (int kt = 0; kt < 8; ++kt) {
    __syncthreads();  // A: prev iter's Ks/Vs readers done before overwrite
    *(uint4*)&Ks[srow*72 + scol]     = kr0;
    *(uint4*)&Ks[srow*72 + scol + 8] = kr1;
    *(uint4*)&Vs[srow*72 + scol]     = vr0;
    *(uint4*)&Vs[srow*72 + scol + 8] = vr1;
    __syncthreads();  // B: staging visible

    // T14: issue NEXT tile's global loads now; consumed at next iter's write.
    if (kt < 7) {
      const u16* kp = kbase + (size_t)((kt+1)*64 + srow)*1536 + scol;
      kr0 = *(const uint4*)kp; kr1 = *(const uint4*)(kp + 8);
      const u16* vp = vbase + (size_t)srow*512 + (kt+1)*64 + scol;
      vr0 = *(const uint4*)vp; vr1 = *(const uint4*)(vp + 8);
    }

    // S^T = K . Q^T  (lane: col=lr -> q fixed, row=quad*4+r -> k-local)
    floatx4 s4[4];
    __builtin_amdgcn_s_setprio(1);
    #pragma unroll
    for (int nt = 0; nt < 4; ++nt) {
      short8 kb0 = *(const short8*)&Ks[(nt*16 + lr)*72 + quad*8];
      short8 kb1 = *(const short8*)&Ks[(nt*16 + lr)*72 + 32 + quad*8];
      floatx4 c = {0.f,0.f,0.f,0.f};
      c = __builtin_amdgcn_mfma_f32_16x16x32_bf16(kb0, af0, c, 0, 0, 0);
      c = __builtin_amdgcn_mfma_f32_16x16x32_bf16(kb1, af1, c, 0, 0, 0);
      s4[nt] = c;
    }
    __builtin_amdgcn_s_setprio(0);

    // P = exp2(S*0.125*log2e + bias), packed to bf16 pairs.
    // Wave-uniform tile classification vs the clamp band:
    const int tmin = kt*64 - (qt*64 + w*16 + 15);   // min dd over wave tile
    const int tmax = tmin + 78;                     // max dd
    u32 wq[4][2];
    const int kq = kt*64 + quad*4 - qglob;
    if (tmin >= 128 || tmax <= -128) {
      // fully clamped: bias constant per lane
      const float pc = (tmin >= 128) ? prHi : prLo;
      #pragma unroll
      for (int nt = 0; nt < 4; ++nt) {
        float p[4];
        #pragma unroll
        for (int r = 0; r < 4; ++r)
          p[r] = exp2f(fmaf(s4[nt][r], 0.18033688f, pc));
        lacc += (p[0] + p[1]) + (p[2] + p[3]);
        wq[nt][0] = cvtpk(p[0], p[1]);
        wq[nt][1] = cvtpk(p[2], p[3]);
      }
    } else if (tmin >= -128 && tmax <= 128) {
      // interior: no clamp needed
      #pragma unroll
      for (int nt = 0; nt < 4; ++nt) {
        const int dbase = kq + nt*16;
        float p[4];
        #pragma unroll
        for (int r = 0; r < 4; ++r)
          p[r] = exp2f(fmaf(s4[nt][r], 0.18033688f, b2f(Pr[prbase + dbase + r])));
        lacc += (p[0] + p[1]) + (p[2] + p[3]);
        wq[nt][0] = cvtpk(p[0], p[1]);
        wq[nt][1] = cvtpk(p[2], p[3]);
      }
    } else {
      // partial: clamped gather (original path)
      #pragma unroll
      for (int nt = 0; nt < 4; ++nt) {
        const int dbase = kq + nt*16;
        float p[4];
        #pragma unroll
        for (int r = 0; r < 4; ++r) {
          int dd = dbase + r;
          dd = dd < -128 ? -128 : (dd > 128 ? 128 : dd);
          p[r] = exp2f(fmaf(s4[nt][r], 0.18033688f, b2f(Pr[prbase + dd])));
        }
        lacc += (p[0] + p[1]) + (p[2] + p[3]);
        wq[nt][0] = cvtpk(p[0], p[1]);
        wq[nt][1] = cvtpk(p[2], p[3]);
      }
    }

    // PV B-fragments assembled in registers (sigma absorbed into vb reads)
    intx4 pw0; pw0.x = (int)wq[0][0]; pw0.y = (int)wq[0][1];
               pw0.z = (int)wq[1][0]; pw0.w = (int)wq[1][1];
    intx4 pw1; pw1.x = (int)wq[2][0]; pw1.y = (int)wq[2][1];
               pw1.z = (int)wq[3][0]; pw1.w = (int)wq[3][1];
    const short8 pf0 = __builtin_bit_cast(short8, pw0);
    const short8 pf1 = __builtin_bit_cast(short8, pw1);

    // O += V x P : A-frag vb[row=d][kk] = V^T[d][sigma(kk)];
    // sigma(kk = quad*8+j) = (j>>2)*16 + quad*4 + (j&3)  (+32 for pf1 half)
    __builtin_amdgcn_s_setprio(1);
    #pragma unroll
    for (int nd = 0; nd < 4; ++nd) {
      const int vrow = (nd*16 + lr)*72;
      uint2 a0 = *(const uint2*)&Vs[vrow + quad*4];
      uint2 a1 = *(const uint2*)&Vs[vrow + 16 + quad*4];
      uint2 a2 = *(const uint2*)&Vs[vrow + 32 + quad*4];
      uint2 a3 = *(const uint2*)&Vs[vrow + 48 + quad*4];
      intx4 v0; v0.x = (int)a0.x; v0.y = (int)a0.y; v0.z = (int)a1.x; v0.w = (int)a1.y;
      intx4 v1; v1.x = (int)a2.x; v1.y = (int)a2.y; v1.z = (int)a3.x; v1.w = (int)a3.y;
      const short8 vb0 = __builtin_bit_cast(short8, v0);
      const short8 vb1 = __builtin_bit_cast(short8, v1);
      oacc[nd] = __builtin_amdgcn_mfma_f32_16x16x32_bf16(vb0, pf0, oacc[nd], 0, 0, 0);
      oacc[nd] = __builtin_amdgcn_mfma_f32_16x16x32_bf16(vb1, pf1, oacc[nd], 0, 0, 0);
    }
    __builtin_amdgcn_s_setprio(0);
  }

  // cross-quad denominator reduce (q = lr is shared by the 4 quads)
  lacc += __shfl_xor(lacc, 16);
  lacc += __shfl_xor(lacc, 32);

  // epilogue: q = lr (fixed per lane); lane writes d = nd*16 + quad*4 + v
  {
    const float inv = 1.f / lacc;
    u16* cp = ctx + (token0 + w*16 + lr)*512 + h*64;
    #pragma unroll
    for (int nd = 0; nd < 4; ++nd) {
      const int d = nd*16 + quad*4;
      uint2 o;
      o.x = pack2(oacc[nd][0]*inv, oacc[nd][1]*inv);
      o.y = pack2(oacc[nd][2]*inv, oacc[nd][3]*inv);
      *(uint2*)(cp + d) = o;
    }
  }
}

// ---------------------------------------------------------------------------
// LayerNorm over D=512, R11 structure: ONE WAVE PER ROW — 64 lanes x 8 elems,
// uint4 bf16 loads (16B/lane), pure shfl_xor reductions. ZERO barriers/LDS.
// R12: add-sources are BF16 partials (one uint4 each, was 2x float4) —
// halves the split-K re-read traffic. 4 rows per 256-thread block.
// ---------------------------------------------------------------------------
__global__ __launch_bounds__(256) void ln_kernel(
    const u16* __restrict__ resB, const u16* __restrict__ add0,
    const u16* __restrict__ add1,
    const float* __restrict__ g, const float* __restrict__ be,
    u16* __restrict__ hb)
{
  const int wv = threadIdx.x >> 6, ln = threadIdx.x & 63;
  const int row = blockIdx.x * 4 + wv;
  const size_t base = (size_t)row * 512;
  const int off = ln * 8;

  const uint4 rv = *(const uint4*)(resB + base + off);
  float x[8];
  x[0] = lo16(rv.x); x[1] = hi16(rv.x);
  x[2] = lo16(rv.y); x[3] = hi16(rv.y);
  x[4] = lo16(rv.z); x[5] = hi16(rv.z);
  x[6] = lo16(rv.w); x[7] = hi16(rv.w);
  if (add0) {
    const uint4 a = *(const uint4*)(add0 + base + off);
    x[0] += lo16(a.x); x[1] += hi16(a.x);
    x[2] += lo16(a.y); x[3] += hi16(a.y);
    x[4] += lo16(a.z); x[5] += hi16(a.z);
    x[6] += lo16(a.w); x[7] += hi16(a.w);
  }
  if (add1) {
    const uint4 a = *(const uint4*)(add1 + base + off);
    x[0] += lo16(a.x); x[1] += hi16(a.x);
    x[2] += lo16(a.y); x[3] += hi16(a.y);
    x[4] += lo16(a.z); x[5] += hi16(a.z);
    x[6] += lo16(a.w); x[7] += hi16(a.w);
  }

  float s = ((x[0]+x[1]) + (x[2]+x[3])) + ((x[4]+x[5]) + (x[6]+x[7]));
  #pragma unroll
  for (int o = 1; o < 64; o <<= 1) s += __shfl_xor(s, o);
  const float mean = s * (1.f/512.f);

  float vs = 0.f;
  #pragma unroll
  for (int i = 0; i < 8; ++i) { const float d = x[i] - mean; vs = fmaf(d, d, vs); }
  #pragma unroll
  for (int o = 1; o < 64; o <<= 1) vs += __shfl_xor(vs, o);
  const float inv = 1.f / sqrtf(vs * (1.f/512.f) + 1e-5f);

  const float4 g0 = *(const float4*)(g + off);
  const float4 g1 = *(const float4*)(g + off + 4);
  const float4 b0 = *(const float4*)(be + off);
  const float4 b1 = *(const float4*)(be + off + 4);
  const float y0 = (x[0]-mean)*inv*g0.x + b0.x;
  const float y1 = (x[1]-mean)*inv*g0.y + b0.y;
  const float y2 = (x[2]-mean)*inv*g0.z + b0.z;
  const float y3 = (x[3]-mean)*inv*g0.w + b0.w;
  const float y4 = (x[4]-mean)*inv*g1.x + b1.x;
  const float y5 = (x[5]-mean)*inv*g1.y + b1.y;
  const float y6 = (x[6]-mean)*inv*g1.z + b1.z;
  const float y7 = (x[7]-mean)*inv*g1.w + b1.w;
  uint4 o;
  o.x = pack2(y0, y1); o.y = pack2(y2, y3);
  o.z = pack2(y4, y5); o.w = pack2(y6, y7);
  *(uint4*)(hb + base + off) = o;
}

// ---------------------------------------------------------------------------
// out[row] = hd1[row][:] . p2_w + p2_b   (256-dot, one wave per row), f32 out
// ---------------------------------------------------------------------------
__global__ __launch_bounds__(256) void head2_kernel(
    const u16* __restrict__ hd1, const float* __restrict__ p2w,
    const float* __restrict__ p2b, float* __restrict__ out)
{
  const int wv = threadIdx.x >> 6, ln = threadIdx.x & 63;
  const int row = blockIdx.x * 4 + wv;
  const u16* hp = hd1 + (size_t)row * 256 + ln*4;
  const u32 h0 = *(const u32*)hp, h1 = *(const u32*)(hp + 2);
  const float4 w = *(const float4*)(p2w + ln*4);
  float acc = lo16(h0)*w.x + hi16(h0)*w.y + lo16(h1)*w.z + hi16(h1)*w.w;
  #pragma unroll
  for (int off = 1; off < 64; off <<= 1) acc += __shfl_xor(acc, off);
  if (ln == 0) out[row] = acc + p2b[0];
}

// ---------------------------------------------------------------------------
extern "C" void kernel_launch(void* const* d_in, const int* in_sizes, int n_in,
                              void* d_out, int out_size, void* d_ws, size_t ws_size,
                              hipStream_t stream) {
  (void)in_sizes; (void)n_in; (void)out_size; (void)ws_size;
  const float* X    = (const float*)d_in[0];
  const float* INW  = (const float*)d_in[1];
  const float* INB  = (const float*)d_in[2];
  const float* WQ   = (const float*)d_in[3];
  const float* WK   = (const float*)d_in[4];
  const float* WV   = (const float*)d_in[5];
  const float* WO   = (const float*)d_in[6];
  const float* BO   = (const float*)d_in[7];
  const float* REL  = (const float*)d_in[8];
  const float* W1   = (const float*)d_in[9];
  const float* B1   = (const float*)d_in[10];
  const float* W2   = (const float*)d_in[11];
  const float* B2   = (const float*)d_in[12];
  const float* LN1G = (const float*)d_in[13];
  const float* LN1B = (const float*)d_in[14];
  const float* LN2G = (const float*)d_in[15];
  const float* LN2B = (const float*)d_in[16];
  const float* ONG  = (const float*)d_in[17];
  const float* ONB  = (const float*)d_in[18];
  const float* P1W  = (const float*)d_in[19];
  const float* P1B  = (const float*)d_in[20];
  const float* P2W  = (const float*)d_in[21];
  const float* P2B  = (const float*)d_in[22];
  float* out = (float*)d_out;

  char* ws = (char*)d_ws;
  u16*   wT    = (u16*)(ws + OFF_WT);
  u16*   hB    = (u16*)(ws + OFF_HB);
  u16*   qkv   = (u16*)(ws + OFF_QKV);
  u16*   ctx   = (u16*)(ws + OFF_CTX);
  u16*   gout0 = (u16*)(ws + OFF_GOUT);    // bf16 split-K partial 0
  u16*   gout1 = (u16*)(ws + OFF_QKV);     // bf16 partial 1 (alias: qkv dead)
  u16*   ff    = (u16*)(ws + OFF_FF);
  u16*   hd1   = (u16*)(ws + OFF_HD1);
  u16*   vTb   = (u16*)(ws + OFF_VT);
  u16*   relBa = (u16*)(ws + OFF_RELB);

  transpose_all<<<4640, 256, 0, stream>>>(WQ, WK, WV, WO, W1, W2, P1W, wT);
  cvt_rel_all<<<386, 256, 0, stream>>>(REL, relBa);
  input_proj<<<NTOK, 128, 0, stream>>>(X, INW, INB, hB);

  for (int l = 0; l < NLAYER; ++l) {
    const u16* wTl = wT + (size_t)l * LSTRIDE;
    // QKV fused: [8192,512] @ [512,1536]; Q,K -> qkv bf16, V -> vT transposed
    gemm_bt<<<dim3(768,1), 256, 0, stream>>>(hB, wTl, nullptr, nullptr, nullptr, qkv, vTb,
                                             8192, 1536, 512, 512, 4);
    attn_mfma<<<1024, 256, 0, stream>>>(qkv, vTb, relBa + l*17408, ctx);
    // Wo + bo, split-K=2 -> bf16 partials
    gemm_bt<<<dim3(256,2), 256, 0, stream>>>(ctx, wTl + 786432, BO + l*512,
                                             gout0, gout1, nullptr, nullptr,
                                             8192, 512, 512, 256, 1);
    ln_kernel<<<2048, 256, 0, stream>>>(hB, gout0, gout1, LN1G + l*512, LN1B + l*512, hB);
    // FFN1: relu(h @ w1 + b1) -> bf16  (overwrites vT scratch - dead)
    gemm_bt<<<dim3(1024,1), 256, 0, stream>>>(hB, wTl + 1048576, B1 + l*2048,
                                              nullptr, nullptr, ff, nullptr,
                                              8192, 2048, 512, 512, 3);
    // FFN2: ff @ w2 + b2, split-K=2 -> bf16 partials
    gemm_bt<<<dim3(256,2), 256, 0, stream>>>(ff, wTl + 2097152, B2 + l*512,
                                             gout0, gout1, nullptr, nullptr,
                                             8192, 512, 2048, 1024, 1);
    ln_kernel<<<2048, 256, 0, stream>>>(hB, gout0, gout1, LN2G + l*512, LN2B + l*512, hB);
  }
  ln_kernel<<<2048, 256, 0, stream>>>(hB, nullptr, nullptr, ONG, ONB, hB);
  // head: relu(h @ p1_w + p1_b) -> bf16 [8192][256]
  gemm_bt<<<dim3(128,1), 256, 0, stream>>>(hB, wT + P1T_OFF, P1B,
                                           nullptr, nullptr, hd1, nullptr,
                                           8192, 256, 512, 512, 3);
  head2_kernel<<<2048, 256, 0, stream>>>(hd1, P2W, P2B, out);
}